// Round 2
// baseline (1926.595 us; speedup 1.0000x reference)
//
#include <hip/hip_runtime.h>
#include <stdint.h>

#define DI __device__ __forceinline__

typedef unsigned short u16;
typedef unsigned int u32;
typedef __attribute__((ext_vector_type(8))) short short8;
typedef __attribute__((ext_vector_type(4))) float floatx4;

// ---------------- geometry ----------------
constexpr int NPIX = 3600;   // 60*60
constexpr int NK   = 3616;   // 3600 padded to multiple of 32 (zero tail)
constexpr int PP   = 4096;   // 64*64 padded pixel grid (image at [2..61]^2)
constexpr int GUARD= 128;    // guard rows on padded-pixel tensors (shifted reads)
constexpr int CIN  = 2048, CI = 512, CQ = 64;

// ---------------- ws layout (bytes) ----------------
constexpr size_t OFF_XPM    = 0;                       // 2*4352*2048*2 = 35,651,584
constexpr size_t OFF_EBUF   = 0;                       // 1024*3600*4   = 14,745,600
constexpr size_t OFF_PBUF   = 16u*1024u*1024u;         // 3600*3616*2   = 26,035,200
constexpr size_t OFF_SACONV = 0;                       // 2*4096*512*2  = 8,388,608
constexpr size_t OFF_SCCONV = 8388608;
constexpr size_t R1_END     = OFF_PBUF + 26035200;     // 42,812,416
constexpr size_t OFF_FEAT1  = R1_END;
constexpr size_t OFF_FEAT2  = OFF_FEAT1 + 8388608;
constexpr size_t OFF_SAPM   = OFF_FEAT2 + 8388608;     // 2*4352*512*2 = 8,912,896
constexpr size_t OFF_SCPM   = OFF_SAPM + 8912896;
constexpr size_t OFF_WT     = OFF_SCPM + 8912896;      // 512*18432*2 = 18,874,368 (time-shared)
constexpr size_t OFF_QC     = OFF_WT;                  // 2*3600*64*2 = 921,600
constexpr size_t OFF_KC     = OFF_QC + 921600;
constexpr size_t OFF_VC     = OFF_KC + 921600;         // 2*3600*512*2 = 7,372,800
constexpr size_t OFF_WQB    = OFF_WT + 9216000;        // 64*512*2  (dead upper WT region)
constexpr size_t OFF_WKB    = OFF_WQB + 65536;
constexpr size_t OFF_WVB    = OFF_WKB + 65536;         // 512*512*2
constexpr size_t OFF_VCM    = OFF_WT + 18874368;       // 2*512*3616*2 = 7,405,568 (shared w/ F2CM)
constexpr size_t OFF_CEN    = OFF_VCM + 7405568;       // 2*512*512*4 = 2,097,152
constexpr size_t OFF_CATT   = OFF_CEN + 2097152;       // 2*512*512*2 = 1,048,576
constexpr size_t WS_NEED    = OFF_CATT + 1048576;      // ~102 MiB

// ---------------- helpers ----------------
DI float b2f(u16 s){ u32 u = ((u32)s)<<16; float f; __builtin_memcpy(&f,&u,4); return f; }
DI u16 f2b(float f){ u32 u; __builtin_memcpy(&u,&f,4); u32 r=(u+0x7fffu+((u>>16)&1u))>>16; return (u16)r; }
DI int pad_of(int n){ int y=n/60, x=n-y*60; return ((y+2)<<6)+x+2; }
DI bool interior(int p){ int py=p>>6, px=p&63; return (py>=2)&&(py<62)&&(px>=2)&&(px<62); }
DI int compact_of(int p){ return ((p>>6)-2)*60 + (p&63) - 2; }
DI void gll16(const void* g, void* l){
  __builtin_amdgcn_global_load_lds((const __attribute__((address_space(1))) void*)g,
                                   (__attribute__((address_space(3))) void*)l, 16, 0, 0);
}
DI float wred_max(float v){
#pragma unroll
  for(int m=32;m;m>>=1) v=fmaxf(v,__shfl_xor(v,m,64));
  return v;
}
DI float wred_min(float v){
#pragma unroll
  for(int m=32;m;m>>=1) v=fminf(v,__shfl_xor(v,m,64));
  return v;
}
DI float wred_sum(float v){
#pragma unroll
  for(int m=32;m;m>>=1) v+=__shfl_xor(v,m,64);
  return v;
}

// ---------------- NT GEMM: C[M,N] = sum_k A[m,k]*B[n,k] (A,B bf16 in ws) ----------------
// MODE 0: conv epilogue  y=relu(bn(acc)), store bf16 at C[p,gc] for interior rows p
// MODE 1: 1x1 conv       y=acc+bias[gc], store at C[compact(p),gc] for interior p
// MODE 2: energy         y=acc+lam*(dR[gr]-dC[gc])^2, f32 store, bounds-masked
// MODE 3: plain f32      bounds-masked f32 store
// MODE 4: PV epilogue    y=gamma*acc+resid[pad(gr),gc], store bf16 at C[pad(gr),gc]
// MODE 5: sc epilogue    y=gamma*acc+resid[gr,gc], store bf16 at C[gr,gc] for interior gr
struct GArgs {
  const u16* A; const u16* B; u16* Cb; float* Cf;
  const u16* resid;
  const float* bn; const float* bias; const float* gamma; const float* lambp;
  const float* dR; const float* dC;
  long sA, sB, sC, sres;
  int M, N, KT, ktps, lda, ldb, ldc, Mclamp, Nclamp;
};

template<int MODE, bool SHIFT>
__global__ __launch_bounds__(256) void k_gemm(GArgs g){
  __shared__ alignas(16) short As[128*32];
  __shared__ alignas(16) short Bs[128*32];
  const int bz = blockIdx.z;
  const u16* Ab = g.A + (long)bz*g.sA;
  const u16* Bb = g.B + (long)bz*g.sB;
  const int m0 = blockIdx.x*128, n0 = blockIdx.y*128;
  const int tid = threadIdx.x, wid = tid>>6, lane = tid&63;
  const int wr = wid>>1, wc = wid&1;
  const int fr = lane&15, fq = lane>>4;
  const int srow = lane>>2;
  const int sbyte = (lane&3)*16;

  floatx4 acc[4][4];
#pragma unroll
  for(int i=0;i<4;i++)
#pragma unroll
    for(int j=0;j<4;j++)
#pragma unroll
      for(int e=0;e<4;e++) acc[i][j][e]=0.f;

  for(int kt=0; kt<g.KT; ++kt){
    int koffA, rshift;
    if (SHIFT){
      const int s = kt / g.ktps;
      const int kb = kt - s*g.ktps;
      koffA = kb*32;
      rshift = (s/3)*64 + (s - (s/3)*3) - 65;  // (ky-1)*64 + (kx-1)
    } else { koffA = kt*32; rshift = 0; }
    const int koffB = kt*32;
    __syncthreads();
#pragma unroll
    for(int h=0; h<2; ++h){
      const int rt = wid*32 + h*16 + srow;
      long ra = m0 + rt;
      if (!SHIFT) ra = (ra > g.Mclamp) ? (long)g.Mclamp : ra;
      ra += rshift;
      gll16((const char*)(Ab + ra*g.lda + koffA) + sbyte, (char*)As + (wid*32 + h*16)*64);
      long rb = n0 + rt;
      rb = (rb > g.Nclamp) ? (long)g.Nclamp : rb;
      gll16((const char*)(Bb + rb*g.ldb + koffB) + sbyte, (char*)Bs + (wid*32 + h*16)*64);
    }
    __syncthreads();
    short8 af[4], bfv[4];
#pragma unroll
    for(int mi=0;mi<4;mi++) af[mi]  = *(const short8*)(As + (wr*64 + mi*16 + fr)*32 + fq*8);
#pragma unroll
    for(int ni=0;ni<4;ni++) bfv[ni] = *(const short8*)(Bs + (wc*64 + ni*16 + fr)*32 + fq*8);
#pragma unroll
    for(int mi=0;mi<4;mi++)
#pragma unroll
      for(int ni=0;ni<4;ni++)
        acc[mi][ni] = __builtin_amdgcn_mfma_f32_16x16x32_bf16(af[mi], bfv[ni], acc[mi][ni], 0,0,0);
  }

  u16* Cb = (MODE==0||MODE==1||MODE==4||MODE==5) ? g.Cb + (long)bz*g.sC : nullptr;
  float* Cf = (MODE==2||MODE==3) ? g.Cf + (long)bz*g.sC : nullptr;
  const u16* Rb = (MODE==4||MODE==5) ? g.resid + (long)bz*g.sres : nullptr;
  float lam=0.f, gam=0.f;
  if constexpr(MODE==2) lam = *g.lambp;
  if constexpr(MODE==4 || MODE==5) gam = *g.gamma;

#pragma unroll
  for(int ni=0;ni<4;ni++){
    const int gc = n0 + wc*64 + ni*16 + fr;
    if (gc >= g.N) continue;
    float cA=0.f, cB=0.f;
    if constexpr(MODE==0){
      const float s=g.bn[gc], bb=g.bn[g.N+gc], mm=g.bn[2*g.N+gc], vv=g.bn[3*g.N+gc];
      cA = s*rsqrtf(vv+1e-5f); cB = bb - cA*mm;
    } else if constexpr(MODE==1){ cA = g.bias[gc]; }
    else if constexpr(MODE==2){ cB = g.dC[gc]; }
#pragma unroll
    for(int mi=0;mi<4;mi++){
#pragma unroll
      for(int j=0;j<4;j++){
        const int gr = m0 + wr*64 + mi*16 + fq*4 + j;
        const float v = acc[mi][ni][j];
        if constexpr(MODE==0){
          if (interior(gr)) Cb[(size_t)gr*g.ldc + gc] = f2b(fmaxf(cA*v+cB, 0.f));
        } else if constexpr(MODE==1){
          if (interior(gr)) Cb[(size_t)compact_of(gr)*g.ldc + gc] = f2b(v + cA);
        } else if constexpr(MODE==2){
          if (gr < g.M){ const float t=g.dR[gr]-cB; Cf[(size_t)gr*g.ldc + gc] = v + lam*t*t; }
        } else if constexpr(MODE==3){
          if (gr < g.M) Cf[(size_t)gr*g.ldc + gc] = v;
        } else if constexpr(MODE==4){
          if (gr < g.M){ const size_t o=(size_t)pad_of(gr)*g.ldc + gc; Cb[o] = f2b(gam*v + b2f(Rb[o])); }
        } else if constexpr(MODE==5){
          if (interior(gr)){ const size_t o=(size_t)gr*g.ldc + gc; Cb[o] = f2b(gam*v + b2f(Rb[o])); }
        }
      }
    }
  }
}

// ---------------- x f32 [B,2048,3600] -> padded pixel-major bf16 [B][4352][2048] ----------------
__global__ __launch_bounds__(256) void k_padx(const float* __restrict__ x, u16* __restrict__ xpm){
  __shared__ alignas(16) u16 t[64][72];
  const int n0 = blockIdx.x*64, c0 = blockIdx.y*64, b = blockIdx.z;
  const float* xb = x + (size_t)b*CIN*NPIX;
  u16* ob = xpm + (size_t)b*(PP+2*GUARD)*CIN + (size_t)GUARD*CIN;
  const int tid = threadIdx.x;
#pragma unroll
  for(int pass=0; pass<2; ++pass){
    const int cl = pass*32 + (tid>>3);
    const int nn = (tid&7)*8;
    const int n = n0 + nn;
    const float* src = xb + (size_t)(c0+cl)*NPIX + n;
    u16 r[8];
    if (n + 7 < NPIX){
      const float4 v0 = *(const float4*)src;
      const float4 v1 = *(const float4*)(src+4);
      r[0]=f2b(v0.x); r[1]=f2b(v0.y); r[2]=f2b(v0.z); r[3]=f2b(v0.w);
      r[4]=f2b(v1.x); r[5]=f2b(v1.y); r[6]=f2b(v1.z); r[7]=f2b(v1.w);
    } else {
#pragma unroll
      for(int j=0;j<8;j++){ const int nj=n+j; r[j] = (nj<NPIX)? f2b(src[j]) : (u16)0; }
    }
    __builtin_memcpy(&t[cl][nn], r, 16);
  }
  __syncthreads();
#pragma unroll
  for(int pass=0; pass<2; ++pass){
    const int nl = pass*32 + (tid>>3);
    const int cc = (tid&7)*8;
    const int n = n0 + nl;
    if (n < NPIX){
      u16 v[8];
#pragma unroll
      for(int j=0;j<8;j++) v[j] = t[cc+j][nl];
      uint4 vv; __builtin_memcpy(&vv, v, 16);
      *(uint4*)(ob + (size_t)pad_of(n)*CIN + c0 + cc) = vv;
    }
  }
}

// ---------------- bf16 [rows, 512] pixel-major -> [512, 3616] channel-major (zero tail) ----------------
template<bool PADIN>
__global__ __launch_bounds__(256) void k_to_cm(const u16* __restrict__ in, u16* __restrict__ out,
                                               long sIn, long sOut){
  __shared__ alignas(16) u16 t[64][72];
  const int n0 = blockIdx.x*64, c0 = blockIdx.y*64, b = blockIdx.z;
  const u16* ib = in + (size_t)b*sIn;
  u16* ob = out + (size_t)b*sOut;
  const int tid = threadIdx.x;
#pragma unroll
  for(int pass=0; pass<2; ++pass){
    const int nl = pass*32 + (tid>>3);
    const int cc = (tid&7)*8;
    const int n = n0 + nl;
    uint4 v = {0,0,0,0};
    if (n < NPIX){
      const int r = PADIN ? pad_of(n) : n;
      v = *(const uint4*)(ib + (size_t)r*CI + c0 + cc);
    }
    *(uint4*)&t[nl][cc] = v;
  }
  __syncthreads();
#pragma unroll
  for(int pass=0; pass<2; ++pass){
    const int cl = pass*32 + (tid>>3);
    const int nn = (tid&7)*8;
    const int n = n0 + nn;
    if (n < NK){
      u16 v[8];
#pragma unroll
      for(int j=0;j<8;j++) v[j] = t[nn+j][cl];
      uint4 vv; __builtin_memcpy(&vv, v, 16);
      *(uint4*)(ob + (size_t)(c0+cl)*NK + n) = vv;
    }
  }
}

// ---------------- w f32 [O,Kc,3,3] -> Wt bf16 [O, 9*Kc], Wt[o, s*Kc+i] = w[o,i,s] ----------------
__global__ __launch_bounds__(256) void k_wt(const float* __restrict__ w, u16* __restrict__ wt, int Kc){
  const int idx = blockIdx.x*256 + threadIdx.x;
  const int o = idx / Kc, i = idx - o*Kc;
  u16 v[9];
#pragma unroll
  for(int s=0;s<9;s++) v[s] = f2b(w[(size_t)idx*9 + s]);
#pragma unroll
  for(int s=0;s<9;s++) wt[(size_t)o*9*Kc + (size_t)s*Kc + i] = v[s];
}

// ---------------- f32 -> bf16 elementwise ----------------
__global__ __launch_bounds__(256) void k_cvt(const float* __restrict__ src, u16* __restrict__ dst, int n){
  const int i = blockIdx.x*256 + threadIdx.x;
  if (i < n) dst[i] = f2b(src[i]);
}

// ---------------- row softmax: E[r, 0..3599] f32 -> P[(c0+r), 0..3615] bf16 ----------------
__global__ __launch_bounds__(256) void k_softmax(const float* __restrict__ E, u16* __restrict__ P, int c0){
  __shared__ float row[NK];
  __shared__ float red[8];
  const int r = blockIdx.x, tid = threadIdx.x;
  const float* e = E + (size_t)r*NPIX;
  float lmax = -3e38f;
  for(int i=tid;i<NK;i+=256){
    const float v = (i<NPIX)? e[i] : -3e38f;
    row[i]=v; lmax=fmaxf(lmax,v);
  }
  lmax = wred_max(lmax);
  if((tid&63)==0) red[tid>>6]=lmax;
  __syncthreads();
  const float m = fmaxf(fmaxf(red[0],red[1]),fmaxf(red[2],red[3]));
  float ls=0.f;
  for(int i=tid;i<NK;i+=256){
    const float v=__expf(row[i]-m);
    row[i]=v; ls+=v;
  }
  ls = wred_sum(ls);
  if((tid&63)==0) red[4+(tid>>6)]=ls;
  __syncthreads();
  const float inv = 1.f/(red[4]+red[5]+red[6]+red[7]);
  u16* po = P + (size_t)(c0+r)*NK;
  for(int i=tid;i<NK;i+=256) po[i]=f2b(row[i]*inv);
}

// ---------------- channel softmax: catt[c,d] = softmax_d(max_d cen - cen) ----------------
__global__ __launch_bounds__(256) void k_csoftmax(const float* __restrict__ cen, u16* __restrict__ catt){
  const int c = blockIdx.x, b = blockIdx.y, tid = threadIdx.x;
  const float* e = cen + ((size_t)b*CI + c)*CI;
  u16* o = catt + ((size_t)b*CI + c)*CI;
  __shared__ float red[8];
  const float a0 = e[tid], a1 = e[tid+256];
  float lmin = fminf(a0,a1);
  lmin = wred_min(lmin);
  if((tid&63)==0) red[tid>>6]=lmin;
  __syncthreads();
  const float m0 = fminf(fminf(red[0],red[1]),fminf(red[2],red[3]));
  const float x0 = __expf(m0-a0), x1 = __expf(m0-a1);
  float ls = x0+x1;
  ls = wred_sum(ls);
  if((tid&63)==0) red[4+(tid>>6)]=ls;
  __syncthreads();
  const float inv = 1.f/(red[4]+red[5]+red[6]+red[7]);
  o[tid] = f2b(x0*inv); o[tid+256] = f2b(x1*inv);
}

// ---------------- fused 1x1 head: 3 f32 outputs from sa_conv/sc_conv (bf16) ----------------
__global__ __launch_bounds__(256) void k_head(const u16* __restrict__ sa, const u16* __restrict__ sc,
    const float* __restrict__ w6, const float* __restrict__ b6,
    const float* __restrict__ w7, const float* __restrict__ b7,
    const float* __restrict__ w8, const float* __restrict__ b8,
    float* __restrict__ out){
  __shared__ float fa[64][65], fb[64][65];
  __shared__ float wf[3][40][64];
  const int n0 = blockIdx.x*64, b = blockIdx.y;
  const u16* sab = sa + (size_t)b*PP*CI;
  const u16* scb = sc + (size_t)b*PP*CI;
  const int tid = threadIdx.x;
  const int px = tid & 63, og = tid >> 6;
  float a6[10], a7[10], a8[10];
#pragma unroll
  for(int i=0;i<10;i++){ a6[i]=0.f; a7[i]=0.f; a8[i]=0.f; }
  for(int cc0=0; cc0<CI; cc0+=64){
    __syncthreads();
#pragma unroll
    for(int pass=0; pass<2; ++pass){
      const int rl = pass*32 + (tid>>3);
      const int cq = (tid&7)*8;
      const int n = n0 + rl;
      const int prow = pad_of(n < NPIX ? n : NPIX-1);
      const uint4 va = *(const uint4*)(sab + (size_t)prow*CI + cc0 + cq);
      const uint4 vb = *(const uint4*)(scb + (size_t)prow*CI + cc0 + cq);
      const u16* pa = (const u16*)&va; const u16* pb = (const u16*)&vb;
#pragma unroll
      for(int j=0;j<8;j++){ fa[rl][cq+j] = b2f(pa[j]); fb[rl][cq+j] = b2f(pb[j]); }
    }
    for(int i=tid; i<40*64; i+=256){
      const int o = i>>6, c = i&63;
      wf[0][o][c] = w6[(size_t)o*CI + cc0 + c];
      wf[1][o][c] = w7[(size_t)o*CI + cc0 + c];
      wf[2][o][c] = w8[(size_t)o*CI + cc0 + c];
    }
    __syncthreads();
    for(int cl=0; cl<64; ++cl){
      const float va = fa[px][cl], vb = fb[px][cl], vs = va+vb;
#pragma unroll
      for(int oo=0;oo<10;oo++){
        const int o = og*10+oo;
        a6[oo] += wf[0][o][cl]*va;
        a7[oo] += wf[1][o][cl]*vb;
        a8[oo] += wf[2][o][cl]*vs;
      }
    }
  }
  const int n = n0 + px;
  if (n < NPIX){
#pragma unroll
    for(int oo=0;oo<10;oo++){
      const int o = og*10+oo;
      out[(size_t)b*144000 + (size_t)o*NPIX + n]          = a8[oo] + b8[o]; // sasc
      out[288000 + (size_t)b*144000 + (size_t)o*NPIX + n] = a6[oo] + b6[o]; // sa_output
      out[576000 + (size_t)b*144000 + (size_t)o*NPIX + n] = a7[oo] + b7[o]; // sc_output
    }
  }
}

// ---------------- launch ----------------
extern "C" void kernel_launch(void* const* d_in, const int* in_sizes, int n_in,
                              void* d_out, int out_size, void* d_ws, size_t ws_size,
                              hipStream_t stream){
  (void)in_sizes; (void)n_in; (void)out_size;
  if (ws_size < WS_NEED) return;

  const float* x    = (const float*)d_in[0];
  const float* dd   = (const float*)d_in[1];
  const float* w_s0 = (const float*)d_in[2];
  const float* bn_s0= (const float*)d_in[3];
  const float* wq   = (const float*)d_in[4];
  const float* bq   = (const float*)d_in[5];
  const float* wk   = (const float*)d_in[6];
  const float* bk   = (const float*)d_in[7];
  const float* wv   = (const float*)d_in[8];
  const float* bv   = (const float*)d_in[9];
  const float* gsa  = (const float*)d_in[10];
  const float* lam  = (const float*)d_in[11];
  const float* w_s1 = (const float*)d_in[12];
  const float* bn_s1= (const float*)d_in[13];
  const float* w6   = (const float*)d_in[14];
  const float* b6   = (const float*)d_in[15];
  const float* w_c0 = (const float*)d_in[16];
  const float* bn_c0= (const float*)d_in[17];
  const float* gsc  = (const float*)d_in[18];
  const float* w_c1 = (const float*)d_in[19];
  const float* bn_c1= (const float*)d_in[20];
  const float* w7   = (const float*)d_in[21];
  const float* b7   = (const float*)d_in[22];
  const float* w8   = (const float*)d_in[23];
  const float* b8   = (const float*)d_in[24];

  char* W = (char*)d_ws;
  u16*   XPM   = (u16*)(W + OFF_XPM);
  float* EB    = (float*)(W + OFF_EBUF);
  u16*   PB    = (u16*)(W + OFF_PBUF);
  u16*   SACONV= (u16*)(W + OFF_SACONV);
  u16*   SCCONV= (u16*)(W + OFF_SCCONV);
  u16*   F1    = (u16*)(W + OFF_FEAT1);
  u16*   F2    = (u16*)(W + OFF_FEAT2);
  u16*   SAPM  = (u16*)(W + OFF_SAPM);
  u16*   SCPM  = (u16*)(W + OFF_SCPM);
  u16*   WT    = (u16*)(W + OFF_WT);
  u16*   QC    = (u16*)(W + OFF_QC);
  u16*   KC    = (u16*)(W + OFF_KC);
  u16*   VC    = (u16*)(W + OFF_VC);
  u16*   WQB   = (u16*)(W + OFF_WQB);
  u16*   WKB   = (u16*)(W + OFF_WKB);
  u16*   WVB   = (u16*)(W + OFF_WVB);
  u16*   VCM   = (u16*)(W + OFF_VCM);
  u16*   F2CM  = VCM;                     // time-shared
  float* CEN   = (float*)(W + OFF_CEN);
  u16*   CATT  = (u16*)(W + OFF_CATT);
  float* OUT   = (float*)d_out;

  // zero padded tensors (ring + guards must be 0 for shifted conv reads)
  hipMemsetAsync(XPM,  0, (size_t)2*(PP+2*GUARD)*CIN*2, stream);
  hipMemsetAsync(SAPM, 0, (size_t)2*(PP+2*GUARD)*CI*2,  stream);
  hipMemsetAsync(SCPM, 0, (size_t)2*(PP+2*GUARD)*CI*2,  stream);

  k_padx<<<dim3(57,32,2),256,0,stream>>>(x, XPM);

  // conv s0: feat1 = bn_relu(conv3(x, w_s0))
  k_wt<<<(512*2048)/256,256,0,stream>>>(w_s0, WT, 2048);
  GArgs a{};
  a.A = XPM + (size_t)GUARD*CIN; a.B = WT; a.Cb = F1;
  a.sA = (long)(PP+2*GUARD)*CIN; a.sB = 0; a.sC = (long)PP*CI;
  a.M = PP; a.N = CI; a.KT = 9*2048/32; a.ktps = 2048/32;
  a.lda = CIN; a.ldb = 9*2048; a.ldc = CI; a.Mclamp = PP-1; a.Nclamp = CI-1;
  a.bn = bn_s0;
  k_gemm<0,true><<<dim3(PP/128, CI/128, 2),256,0,stream>>>(a);
  // conv c0: feat2
  k_wt<<<(512*2048)/256,256,0,stream>>>(w_c0, WT, 2048);
  a.bn = bn_c0; a.Cb = F2;
  k_gemm<0,true><<<dim3(PP/128, CI/128, 2),256,0,stream>>>(a);

  // bf16 copies of 1x1 weights (upper WT region is dead now)
  k_cvt<<<(64*512+255)/256,256,0,stream>>>(wq, WQB, 64*512);
  k_cvt<<<(64*512+255)/256,256,0,stream>>>(wk, WKB, 64*512);
  k_cvt<<<(512*512+255)/256,256,0,stream>>>(wv, WVB, 512*512);

  // q, k, v (1x1 convs on feat1, compact pixel-major outputs)
  GArgs q{};
  q.A = F1; q.sA = (long)PP*CI; q.lda = CI;
  q.M = PP; q.Mclamp = PP-1; q.KT = CI/32; q.ktps = 1;
  q.B = WQB; q.sB = 0; q.ldb = CI; q.N = CQ; q.Nclamp = CQ-1;
  q.Cb = QC; q.sC = (long)NPIX*CQ; q.ldc = CQ; q.bias = bq;
  k_gemm<1,false><<<dim3(PP/128, 1, 2),256,0,stream>>>(q);
  q.B = WKB; q.Cb = KC; q.bias = bk;
  k_gemm<1,false><<<dim3(PP/128, 1, 2),256,0,stream>>>(q);
  q.B = WVB; q.Cb = VC; q.bias = bv; q.N = CI; q.Nclamp = CI-1; q.sC = (long)NPIX*CI; q.ldc = CI;
  k_gemm<1,false><<<dim3(PP/128, CI/128, 2),256,0,stream>>>(q);

  k_to_cm<false><<<dim3(57, CI/64, 2),256,0,stream>>>(VC, VCM, (long)NPIX*CI, (long)CI*NK);

  // position attention, per batch: E (chunked) -> softmax -> PV
  for(int bb=0; bb<2; ++bb){
    for(int c0=0; c0<NPIX; c0+=1024){
      int Mc = NPIX - c0; if (Mc > 1024) Mc = 1024;
      GArgs e{};
      e.A = QC + (size_t)bb*NPIX*CQ + (size_t)c0*CQ;
      e.B = KC + (size_t)bb*NPIX*CQ;
      e.Cf = EB;
      e.M = Mc; e.N = NPIX; e.KT = CQ/32; e.ktps = 1;
      e.lda = CQ; e.ldb = CQ; e.ldc = NPIX;
      e.Mclamp = Mc-1; e.Nclamp = NPIX-1;
      e.dR = dd + (size_t)bb*NPIX + c0; e.dC = dd + (size_t)bb*NPIX; e.lambp = lam;
      k_gemm<2,false><<<dim3((Mc+127)/128, (NPIX+127)/128, 1),256,0,stream>>>(e);
      k_softmax<<<Mc,256,0,stream>>>(EB, PB, c0);
    }
    GArgs p{};
    p.A = PB; p.B = VCM + (size_t)bb*CI*NK;
    p.Cb = SAPM + (size_t)bb*(PP+2*GUARD)*CI + (size_t)GUARD*CI;
    p.resid = F1 + (size_t)bb*PP*CI;
    p.gamma = gsa;
    p.M = NPIX; p.N = CI; p.KT = NK/32; p.ktps = 1;
    p.lda = NK; p.ldb = NK; p.ldc = CI;
    p.Mclamp = NPIX-1; p.Nclamp = CI-1;
    k_gemm<4,false><<<dim3((NPIX+127)/128, CI/128, 1),256,0,stream>>>(p);
  }

  // channel attention
  k_to_cm<true><<<dim3(57, CI/64, 2),256,0,stream>>>(F2, F2CM, (long)PP*CI, (long)CI*NK);
  GArgs c{};
  c.A = F2CM; c.B = F2CM; c.Cf = CEN;
  c.sA = (long)CI*NK; c.sB = (long)CI*NK; c.sC = (long)CI*CI;
  c.M = CI; c.N = CI; c.KT = NK/32; c.ktps = 1;
  c.lda = NK; c.ldb = NK; c.ldc = CI; c.Mclamp = CI-1; c.Nclamp = CI-1;
  k_gemm<3,false><<<dim3(CI/128, CI/128, 2),256,0,stream>>>(c);
  k_csoftmax<<<dim3(CI,2),256,0,stream>>>(CEN, CATT);
  GArgs s{};
  s.A = F2; s.B = CATT;
  s.Cb = SCPM + (size_t)GUARD*CI;
  s.resid = F2; s.gamma = gsc;
  s.sA = (long)PP*CI; s.sB = (long)CI*CI; s.sC = (long)(PP+2*GUARD)*CI; s.sres = (long)PP*CI;
  s.M = PP; s.N = CI; s.KT = CI/32; s.ktps = 1;
  s.lda = CI; s.ldb = CI; s.ldc = CI; s.Mclamp = PP-1; s.Nclamp = CI-1;
  k_gemm<5,false><<<dim3(PP/128, CI/128, 2),256,0,stream>>>(s);

  // post convs s1 / c1
  k_wt<<<(512*512)/256,256,0,stream>>>(w_s1, WT, 512);
  GArgs t{};
  t.A = SAPM + (size_t)GUARD*CI; t.B = WT; t.Cb = SACONV;
  t.sA = (long)(PP+2*GUARD)*CI; t.sB = 0; t.sC = (long)PP*CI;
  t.M = PP; t.N = CI; t.KT = 9*512/32; t.ktps = 512/32;
  t.lda = CI; t.ldb = 9*512; t.ldc = CI; t.Mclamp = PP-1; t.Nclamp = CI-1;
  t.bn = bn_s1;
  k_gemm<0,true><<<dim3(PP/128, CI/128, 2),256,0,stream>>>(t);
  k_wt<<<(512*512)/256,256,0,stream>>>(w_c1, WT, 512);
  t.A = SCPM + (size_t)GUARD*CI; t.Cb = SCCONV; t.bn = bn_c1;
  k_gemm<0,true><<<dim3(PP/128, CI/128, 2),256,0,stream>>>(t);

  // fused heads
  k_head<<<dim3(57,2),256,0,stream>>>(SACONV, SCCONV, w6,b6,w7,b7,w8,b8, OUT);
}

// Round 3
// 1232.850 us; speedup vs baseline: 1.5627x; 1.5627x over previous
//
#include <hip/hip_runtime.h>
#include <stdint.h>

#define DI __device__ __forceinline__

typedef unsigned short u16;
typedef unsigned int u32;
typedef __attribute__((ext_vector_type(8))) short short8;
typedef __attribute__((ext_vector_type(4))) float floatx4;

// ---------------- geometry ----------------
constexpr int NPIX = 3600;   // 60*60
constexpr int NK   = 3616;   // 3600 padded to multiple of 32 (zero tail)
constexpr int PP   = 4096;   // 64*64 padded pixel grid (image at [2..61]^2)
constexpr int GUARD= 128;    // guard rows on padded-pixel tensors (shifted reads)
constexpr int CIN  = 2048, CI = 512, CQ = 64;

// ---------------- ws layout (bytes) ----------------
// R1 time-shared: XPM (convs) -> EBUF/PBUF (attention) -> SACONV/SCCONV (tail)
constexpr size_t OFF_XPM    = 0;                       // 2*4352*2048*2 = 35,651,584
constexpr size_t OFF_EBUF   = 0;                       // 1024*3600*4   = 14,745,600
constexpr size_t OFF_PBUF   = 16777216;                // 3600*3616*2   = 26,035,200
constexpr size_t OFF_SACONV = 0;                       // 4096*512*2*2b = 8,388,608
constexpr size_t OFF_SCCONV = 8388608;
constexpr size_t R1_END     = 42812416;
constexpr size_t OFF_FEAT1  = R1_END;                  // 8,388,608
constexpr size_t OFF_FEAT2  = OFF_FEAT1 + 8388608;
constexpr size_t OFF_SAPM   = OFF_FEAT2 + 8388608;     // 8,912,896
constexpr size_t OFF_SCPM   = OFF_SAPM + 8912896;
constexpr size_t OFF_W      = OFF_SCPM + 8912896;      // big region, 37,748,736 (WTT 1024x18432)
// inside W (time-shared with WTT / each other):
constexpr size_t OFF_WQB = OFF_W;                      // 64*512*2
constexpr size_t OFF_WKB = OFF_W + 65536;              // 64*512*2  (contiguous with WQB: 640x512 concat)
constexpr size_t OFF_WVB = OFF_W + 131072;             // 512*512*2
constexpr size_t OFF_QC  = OFF_W + 655360;             // 2*3600*64*2
constexpr size_t OFF_KC  = OFF_W + 1576960;
constexpr size_t OFF_VC  = OFF_W + 2498560;            // 2*3600*512*2 -> end 9,871,360
constexpr size_t OFF_WT1 = OFF_W;                      // 512*4608*2 (s1)  — after QC/KC/VC dead
constexpr size_t OFF_WT2 = OFF_W + 4718592;            // 512*4608*2 (c1)
constexpr size_t OFF_VCM = OFF_W + 9871360;            // 2*512*3616*2 = 7,405,568 (shared w/ F2CM)
constexpr size_t OFF_CEN = OFF_W + 17276928;           // 2*512*512*4 = 2,097,152
constexpr size_t OFF_CATT= OFF_W + 19374080;           // 2*512*512*2 = 1,048,576
constexpr size_t WS_NEED = OFF_W + 37748736;           // 115,164,160 (~110 MiB)

// ---------------- helpers ----------------
DI float b2f(u16 s){ u32 u = ((u32)s)<<16; float f; __builtin_memcpy(&f,&u,4); return f; }
DI u16 f2b(float f){ u32 u; __builtin_memcpy(&u,&f,4); u32 r=(u+0x7fffu+((u>>16)&1u))>>16; return (u16)r; }
DI int pad_of(int n){ int y=n/60, x=n-y*60; return ((y+2)<<6)+x+2; }
DI bool interior(int p){ int py=p>>6, px=p&63; return (py>=2)&&(py<62)&&(px>=2)&&(px<62); }
DI int compact_of(int p){ return ((p>>6)-2)*60 + (p&63) - 2; }
DI void gll16(const void* g, void* l){
  __builtin_amdgcn_global_load_lds((const __attribute__((address_space(1))) void*)g,
                                   (__attribute__((address_space(3))) void*)l, 16, 0, 0);
}
DI float wred_max(float v){
#pragma unroll
  for(int m=32;m;m>>=1) v=fmaxf(v,__shfl_xor(v,m,64));
  return v;
}
DI float wred_min(float v){
#pragma unroll
  for(int m=32;m;m>>=1) v=fminf(v,__shfl_xor(v,m,64));
  return v;
}
DI float wred_sum(float v){
#pragma unroll
  for(int m=32;m;m>>=1) v+=__shfl_xor(v,m,64);
  return v;
}

// ---------------- NT GEMM: C[M,N] = sum_k A[m,k]*B[n,k] (A,B bf16) ----------------
// MODE 0: conv epilogue  relu(bn(acc)) -> bf16 C[p,oc], interior p. NCAT: gc>=nsplit -> {Cb2,bn2}.
//         DUALZ: bz>>1 selects {A2,B2,Cb2,bn2}, bz&1 = batch.
// MODE 2: energy acc+lam*(dR-dC)^2 -> f32
// MODE 3: plain f32
// MODE 4: PV: gamma*acc+resid[pad(gr),gc] -> bf16 C[pad(gr),gc]
// MODE 5: sc: gamma*acc+resid[gr,gc] -> bf16, interior gr
// MODE 6: qkv concat: gc<64 -> QC(+bq), <128 -> KC(+bk), else VC(+bv); compact rows
struct GArgs {
  const u16 *A, *A2, *B, *B2; u16 *Cb, *Cb2, *Cb3; float* Cf;
  const u16* resid;
  const float *bn, *bn2, *bias, *bias2, *bias3, *gamma, *lambp, *dR, *dC;
  long sA, sB, sC, sres;
  int M, N, KT, ktps, lda, ldb, ldc, Mclamp, Nclamp, nsplit;
};

template<int MODE, bool SHIFT, bool NCAT, bool DUALZ>
__global__ __launch_bounds__(256) void k_gemm(GArgs g){
  __shared__ alignas(16) short As[128*32];
  __shared__ alignas(16) short Bs[128*32];
  const int bz = blockIdx.z;
  const int sel = DUALZ ? (bz>>1) : 0;
  const int bt  = DUALZ ? (bz&1)  : bz;
  const u16* Ab = ((DUALZ && sel) ? g.A2 : g.A) + (long)bt*g.sA;
  const u16* Bb = ((DUALZ && sel) ? g.B2 : g.B) + (long)bt*g.sB;
  const int m0 = blockIdx.x*128, n0 = blockIdx.y*128;
  const int tid = threadIdx.x, wid = tid>>6, lane = tid&63;
  const int wr = wid>>1, wc = wid&1;
  const int fr = lane&15, fq = lane>>4;
  const int srow = lane>>2;
  const int swz = ((lane&3) ^ ((lane>>3)&3)) << 3;   // swizzled 8-short slot within 32-short row

  // staging source bases (in shorts)
  long raB[2], rbB[2];
#pragma unroll
  for(int h=0;h<2;h++){
    long ra = m0 + wid*32 + h*16 + srow;
    if (!SHIFT) ra = (ra > g.Mclamp) ? (long)g.Mclamp : ra;
    raB[h] = ra*(long)g.lda + swz;
    long rb = n0 + wid*32 + h*16 + srow;
    rb = (rb > g.Nclamp) ? (long)g.Nclamp : rb;
    rbB[h] = rb*(long)g.ldb + swz;
  }
  char* ldsA[2] = { (char*)As + (size_t)(wid*32)*64, (char*)As + (size_t)(wid*32+16)*64 };
  char* ldsB[2] = { (char*)Bs + (size_t)(wid*32)*64, (char*)Bs + (size_t)(wid*32+16)*64 };
  const int rswz = (fq ^ ((fr>>1)&3)) << 3;          // read-side slot (same involution)
  const short* aRd = As + (wr*64+fr)*32 + rswz;
  const short* bRd = Bs + (wc*64+fr)*32 + rswz;

  floatx4 acc[4][4];
#pragma unroll
  for(int i=0;i<4;i++)
#pragma unroll
    for(int j=0;j<4;j++)
#pragma unroll
      for(int e=0;e<4;e++) acc[i][j][e]=0.f;

  const int NSEG = SHIFT ? 9 : 1;
  const int KB = SHIFT ? g.ktps : g.KT;
  for(int s=0; s<NSEG; ++s){
    const long aoff = SHIFT ? (long)((s/3)*64 + (s-(s/3)*3) - 65)*g.lda : 0; // (ky-1)*64+(kx-1)
    const long boff = (long)s*KB*32;
    for(int kb=0; kb<KB; ++kb){
      const int ko = kb*32;
      __syncthreads();
#pragma unroll
      for(int h=0;h<2;h++){
        gll16(Ab + raB[h] + aoff + ko, ldsA[h]);
        gll16(Bb + rbB[h] + boff + ko, ldsB[h]);
      }
      __syncthreads();
      short8 af[4], bfv[4];
#pragma unroll
      for(int mi=0;mi<4;mi++) af[mi]  = *(const short8*)(aRd + mi*512);
#pragma unroll
      for(int ni=0;ni<4;ni++) bfv[ni] = *(const short8*)(bRd + ni*512);
#pragma unroll
      for(int mi=0;mi<4;mi++)
#pragma unroll
        for(int ni=0;ni<4;ni++)
          acc[mi][ni] = __builtin_amdgcn_mfma_f32_16x16x32_bf16(af[mi], bfv[ni], acc[mi][ni], 0,0,0);
    }
  }

  float* Cf = (MODE==2||MODE==3) ? g.Cf + (long)bt*g.sC : nullptr;
  const u16* Rb = (MODE==4||MODE==5) ? g.resid + (long)bt*g.sres : nullptr;
  float lamv=0.f, gamv=0.f;
  if constexpr(MODE==2) lamv = *g.lambp;
  if constexpr(MODE==4 || MODE==5) gamv = *g.gamma;

#pragma unroll
  for(int ni=0;ni<4;ni++){
    const int gc = n0 + wc*64 + ni*16 + fr;
    if (gc >= g.N) continue;
    if constexpr(MODE==0){
      const float* bnP = g.bn; u16* CbP = g.Cb; int oc = gc;
      if constexpr(DUALZ){ if (sel){ bnP = g.bn2; CbP = g.Cb2; } }
      if constexpr(NCAT){ if (gc >= g.nsplit){ bnP = g.bn2; CbP = g.Cb2; oc = gc - g.nsplit; } }
      CbP += (long)bt*g.sC;
      const float s_=bnP[oc], bb=bnP[CI+oc], mm=bnP[2*CI+oc], vv=bnP[3*CI+oc];
      const float cA = s_*rsqrtf(vv+1e-5f), cB = bb - cA*mm;
#pragma unroll
      for(int mi=0;mi<4;mi++)
#pragma unroll
        for(int j=0;j<4;j++){
          const int gr = m0 + wr*64 + mi*16 + fq*4 + j;
          if (interior(gr)) CbP[(size_t)gr*g.ldc + oc] = f2b(fmaxf(cA*acc[mi][ni][j]+cB, 0.f));
        }
    } else if constexpr(MODE==6){
      u16* dst; int col, ld; float bs;
      if (gc < 64){ dst = g.Cb  + (long)bt*((long)NPIX*CQ); col=gc;     ld=CQ; bs=g.bias[gc]; }
      else if (gc < 128){ dst = g.Cb2 + (long)bt*((long)NPIX*CQ); col=gc-64; ld=CQ; bs=g.bias2[gc-64]; }
      else { dst = g.Cb3 + (long)bt*((long)NPIX*CI); col=gc-128; ld=CI; bs=g.bias3[gc-128]; }
#pragma unroll
      for(int mi=0;mi<4;mi++)
#pragma unroll
        for(int j=0;j<4;j++){
          const int gr = m0 + wr*64 + mi*16 + fq*4 + j;
          if (interior(gr)) dst[(size_t)compact_of(gr)*ld + col] = f2b(acc[mi][ni][j] + bs);
        }
    } else if constexpr(MODE==2){
      const float dc = g.dC[gc];
#pragma unroll
      for(int mi=0;mi<4;mi++)
#pragma unroll
        for(int j=0;j<4;j++){
          const int gr = m0 + wr*64 + mi*16 + fq*4 + j;
          if (gr < g.M){ const float t=g.dR[gr]-dc; Cf[(size_t)gr*g.ldc + gc] = acc[mi][ni][j] + lamv*t*t; }
        }
    } else if constexpr(MODE==3){
#pragma unroll
      for(int mi=0;mi<4;mi++)
#pragma unroll
        for(int j=0;j<4;j++){
          const int gr = m0 + wr*64 + mi*16 + fq*4 + j;
          if (gr < g.M) Cf[(size_t)gr*g.ldc + gc] = acc[mi][ni][j];
        }
    } else if constexpr(MODE==4){
      u16* CbP = g.Cb + (long)bt*g.sC;
#pragma unroll
      for(int mi=0;mi<4;mi++)
#pragma unroll
        for(int j=0;j<4;j++){
          const int gr = m0 + wr*64 + mi*16 + fq*4 + j;
          if (gr < g.M){ const size_t o=(size_t)pad_of(gr)*g.ldc + gc; CbP[o] = f2b(gamv*acc[mi][ni][j] + b2f(Rb[o])); }
        }
    } else if constexpr(MODE==5){
      u16* CbP = g.Cb + (long)bt*g.sC;
#pragma unroll
      for(int mi=0;mi<4;mi++)
#pragma unroll
        for(int j=0;j<4;j++){
          const int gr = m0 + wr*64 + mi*16 + fq*4 + j;
          if (interior(gr)){ const size_t o=(size_t)gr*g.ldc + gc; CbP[o] = f2b(gamv*acc[mi][ni][j] + b2f(Rb[o])); }
        }
    }
  }
}

// ---------------- x f32 [B,2048,3600] -> padded pixel-major bf16 [B][4352][2048] ----------------
__global__ __launch_bounds__(256) void k_padx(const float* __restrict__ x, u16* __restrict__ xpm){
  __shared__ alignas(16) u16 t[64][72];
  const int n0 = blockIdx.x*64, c0 = blockIdx.y*64, b = blockIdx.z;
  const float* xb = x + (size_t)b*CIN*NPIX;
  u16* ob = xpm + (size_t)b*(PP+2*GUARD)*CIN + (size_t)GUARD*CIN;
  const int tid = threadIdx.x;
#pragma unroll
  for(int pass=0; pass<2; ++pass){
    const int cl = pass*32 + (tid>>3);
    const int nn = (tid&7)*8;
    const int n = n0 + nn;
    const float* src = xb + (size_t)(c0+cl)*NPIX + n;
    u16 r[8];
    if (n + 7 < NPIX){
      const float4 v0 = *(const float4*)src;
      const float4 v1 = *(const float4*)(src+4);
      r[0]=f2b(v0.x); r[1]=f2b(v0.y); r[2]=f2b(v0.z); r[3]=f2b(v0.w);
      r[4]=f2b(v1.x); r[5]=f2b(v1.y); r[6]=f2b(v1.z); r[7]=f2b(v1.w);
    } else {
#pragma unroll
      for(int j=0;j<8;j++){ const int nj=n+j; r[j] = (nj<NPIX)? f2b(src[j]) : (u16)0; }
    }
    __builtin_memcpy(&t[cl][nn], r, 16);
  }
  __syncthreads();
#pragma unroll
  for(int pass=0; pass<2; ++pass){
    const int nl = pass*32 + (tid>>3);
    const int cc = (tid&7)*8;
    const int n = n0 + nl;
    if (n < NPIX){
      u16 v[8];
#pragma unroll
      for(int j=0;j<8;j++) v[j] = t[cc+j][nl];
      uint4 vv; __builtin_memcpy(&vv, v, 16);
      *(uint4*)(ob + (size_t)pad_of(n)*CIN + c0 + cc) = vv;
    }
  }
}

// ---------------- bf16 [rows, 512] pixel-major -> [512, 3616] channel-major (zero tail) ----------------
template<bool PADIN>
__global__ __launch_bounds__(256) void k_to_cm(const u16* __restrict__ in, u16* __restrict__ out,
                                               long sIn, long sOut){
  __shared__ alignas(16) u16 t[64][72];
  const int n0 = blockIdx.x*64, c0 = blockIdx.y*64, b = blockIdx.z;
  const u16* ib = in + (size_t)b*sIn;
  u16* ob = out + (size_t)b*sOut;
  const int tid = threadIdx.x;
#pragma unroll
  for(int pass=0; pass<2; ++pass){
    const int nl = pass*32 + (tid>>3);
    const int cc = (tid&7)*8;
    const int n = n0 + nl;
    uint4 v = {0,0,0,0};
    if (n < NPIX){
      const int r = PADIN ? pad_of(n) : n;
      v = *(const uint4*)(ib + (size_t)r*CI + c0 + cc);
    }
    *(uint4*)&t[nl][cc] = v;
  }
  __syncthreads();
#pragma unroll
  for(int pass=0; pass<2; ++pass){
    const int cl = pass*32 + (tid>>3);
    const int nn = (tid&7)*8;
    const int n = n0 + nn;
    if (n < NK){
      u16 v[8];
#pragma unroll
      for(int j=0;j<8;j++) v[j] = t[nn+j][cl];
      uint4 vv; __builtin_memcpy(&vv, v, 16);
      *(uint4*)(ob + (size_t)(c0+cl)*NK + n) = vv;
    }
  }
}

// ---------------- w f32 [O,Kc,3,3] -> Wt bf16 [O, 9*Kc], Wt[o, s*Kc+i] = w[o,i,s] ----------------
__global__ __launch_bounds__(256) void k_wt(const float* __restrict__ w, u16* __restrict__ wt, int Kc){
  const int idx = blockIdx.x*256 + threadIdx.x;
  const int o = idx / Kc, i = idx - o*Kc;
  u16 v[9];
#pragma unroll
  for(int s=0;s<9;s++) v[s] = f2b(w[(size_t)idx*9 + s]);
#pragma unroll
  for(int s=0;s<9;s++) wt[(size_t)o*9*Kc + (size_t)s*Kc + i] = v[s];
}

// ---------------- f32 -> bf16 elementwise ----------------
__global__ __launch_bounds__(256) void k_cvt(const float* __restrict__ src, u16* __restrict__ dst, int n){
  const int i = blockIdx.x*256 + threadIdx.x;
  if (i < n) dst[i] = f2b(src[i]);
}

// ---------------- row softmax: E[r, 0..3599] f32 -> P[(c0+r), 0..3615] bf16 ----------------
__global__ __launch_bounds__(256) void k_softmax(const float* __restrict__ E, u16* __restrict__ P, int c0){
  __shared__ float row[NK];
  __shared__ float red[8];
  const int r = blockIdx.x, tid = threadIdx.x;
  const float* e = E + (size_t)r*NPIX;
  float lmax = -3e38f;
  for(int i=tid;i<NK;i+=256){
    const float v = (i<NPIX)? e[i] : -3e38f;
    row[i]=v; lmax=fmaxf(lmax,v);
  }
  lmax = wred_max(lmax);
  if((tid&63)==0) red[tid>>6]=lmax;
  __syncthreads();
  const float m = fmaxf(fmaxf(red[0],red[1]),fmaxf(red[2],red[3]));
  float ls=0.f;
  for(int i=tid;i<NK;i+=256){
    const float v=__expf(row[i]-m);
    row[i]=v; ls+=v;
  }
  ls = wred_sum(ls);
  if((tid&63)==0) red[4+(tid>>6)]=ls;
  __syncthreads();
  const float inv = 1.f/(red[4]+red[5]+red[6]+red[7]);
  u16* po = P + (size_t)(c0+r)*NK;
  for(int i=tid;i<NK;i+=256) po[i]=f2b(row[i]*inv);
}

// ---------------- channel softmax: catt[c,d] = softmax_d(max_d cen - cen) ----------------
__global__ __launch_bounds__(256) void k_csoftmax(const float* __restrict__ cen, u16* __restrict__ catt){
  const int c = blockIdx.x, b = blockIdx.y, tid = threadIdx.x;
  const float* e = cen + ((size_t)b*CI + c)*CI;
  u16* o = catt + ((size_t)b*CI + c)*CI;
  __shared__ float red[8];
  const float a0 = e[tid], a1 = e[tid+256];
  float lmin = fminf(a0,a1);
  lmin = wred_min(lmin);
  if((tid&63)==0) red[tid>>6]=lmin;
  __syncthreads();
  const float m0 = fminf(fminf(red[0],red[1]),fminf(red[2],red[3]));
  const float x0 = __expf(m0-a0), x1 = __expf(m0-a1);
  float ls = x0+x1;
  ls = wred_sum(ls);
  if((tid&63)==0) red[4+(tid>>6)]=ls;
  __syncthreads();
  const float inv = 1.f/(red[4]+red[5]+red[6]+red[7]);
  o[tid] = f2b(x0*inv); o[tid+256] = f2b(x1*inv);
}

// ---------------- fused 1x1 head: 3 f32 outputs from sa_conv/sc_conv (bf16) ----------------
__global__ __launch_bounds__(256) void k_head(const u16* __restrict__ sa, const u16* __restrict__ sc,
    const float* __restrict__ w6, const float* __restrict__ b6,
    const float* __restrict__ w7, const float* __restrict__ b7,
    const float* __restrict__ w8, const float* __restrict__ b8,
    float* __restrict__ out){
  __shared__ float fa[64][65], fb[64][65];
  __shared__ float wf[3][40][64];
  const int n0 = blockIdx.x*64, b = blockIdx.y;
  const u16* sab = sa + (size_t)b*PP*CI;
  const u16* scb = sc + (size_t)b*PP*CI;
  const int tid = threadIdx.x;
  const int px = tid & 63, og = tid >> 6;
  float a6[10], a7[10], a8[10];
#pragma unroll
  for(int i=0;i<10;i++){ a6[i]=0.f; a7[i]=0.f; a8[i]=0.f; }
  for(int cc0=0; cc0<CI; cc0+=64){
    __syncthreads();
#pragma unroll
    for(int pass=0; pass<2; ++pass){
      const int rl = pass*32 + (tid>>3);
      const int cq = (tid&7)*8;
      const int n = n0 + rl;
      const int prow = pad_of(n < NPIX ? n : NPIX-1);
      const uint4 va = *(const uint4*)(sab + (size_t)prow*CI + cc0 + cq);
      const uint4 vb = *(const uint4*)(scb + (size_t)prow*CI + cc0 + cq);
      const u16* pa = (const u16*)&va; const u16* pb = (const u16*)&vb;
#pragma unroll
      for(int j=0;j<8;j++){ fa[rl][cq+j] = b2f(pa[j]); fb[rl][cq+j] = b2f(pb[j]); }
    }
    for(int i=tid; i<40*64; i+=256){
      const int o = i>>6, c = i&63;
      wf[0][o][c] = w6[(size_t)o*CI + cc0 + c];
      wf[1][o][c] = w7[(size_t)o*CI + cc0 + c];
      wf[2][o][c] = w8[(size_t)o*CI + cc0 + c];
    }
    __syncthreads();
    for(int cl=0; cl<64; ++cl){
      const float va = fa[px][cl], vb = fb[px][cl], vs = va+vb;
#pragma unroll
      for(int oo=0;oo<10;oo++){
        const int o = og*10+oo;
        a6[oo] += wf[0][o][cl]*va;
        a7[oo] += wf[1][o][cl]*vb;
        a8[oo] += wf[2][o][cl]*vs;
      }
    }
  }
  const int n = n0 + px;
  if (n < NPIX){
#pragma unroll
    for(int oo=0;oo<10;oo++){
      const int o = og*10+oo;
      out[(size_t)b*144000 + (size_t)o*NPIX + n]          = a8[oo] + b8[o]; // sasc
      out[288000 + (size_t)b*144000 + (size_t)o*NPIX + n] = a6[oo] + b6[o]; // sa_output
      out[576000 + (size_t)b*144000 + (size_t)o*NPIX + n] = a7[oo] + b7[o]; // sc_output
    }
  }
}

// ---------------- launch ----------------
extern "C" void kernel_launch(void* const* d_in, const int* in_sizes, int n_in,
                              void* d_out, int out_size, void* d_ws, size_t ws_size,
                              hipStream_t stream){
  (void)in_sizes; (void)n_in; (void)out_size;
  if (ws_size < WS_NEED) return;

  const float* x    = (const float*)d_in[0];
  const float* dd   = (const float*)d_in[1];
  const float* w_s0 = (const float*)d_in[2];
  const float* bn_s0= (const float*)d_in[3];
  const float* wq   = (const float*)d_in[4];
  const float* bq   = (const float*)d_in[5];
  const float* wk   = (const float*)d_in[6];
  const float* bk   = (const float*)d_in[7];
  const float* wv   = (const float*)d_in[8];
  const float* bv   = (const float*)d_in[9];
  const float* gsa  = (const float*)d_in[10];
  const float* lam  = (const float*)d_in[11];
  const float* w_s1 = (const float*)d_in[12];
  const float* bn_s1= (const float*)d_in[13];
  const float* w6   = (const float*)d_in[14];
  const float* b6   = (const float*)d_in[15];
  const float* w_c0 = (const float*)d_in[16];
  const float* bn_c0= (const float*)d_in[17];
  const float* gsc  = (const float*)d_in[18];
  const float* w_c1 = (const float*)d_in[19];
  const float* bn_c1= (const float*)d_in[20];
  const float* w7   = (const float*)d_in[21];
  const float* b7   = (const float*)d_in[22];
  const float* w8   = (const float*)d_in[23];
  const float* b8   = (const float*)d_in[24];

  char* W = (char*)d_ws;
  u16*   XPM   = (u16*)(W + OFF_XPM);
  float* EB    = (float*)(W + OFF_EBUF);
  u16*   PB    = (u16*)(W + OFF_PBUF);
  u16*   SACONV= (u16*)(W + OFF_SACONV);
  u16*   SCCONV= (u16*)(W + OFF_SCCONV);
  u16*   F1    = (u16*)(W + OFF_FEAT1);
  u16*   F2    = (u16*)(W + OFF_FEAT2);
  u16*   SAPM  = (u16*)(W + OFF_SAPM);
  u16*   SCPM  = (u16*)(W + OFF_SCPM);
  u16*   WTT   = (u16*)(W + OFF_W);
  u16*   WQB   = (u16*)(W + OFF_WQB);
  u16*   WKB   = (u16*)(W + OFF_WKB);
  u16*   WVB   = (u16*)(W + OFF_WVB);
  u16*   QC    = (u16*)(W + OFF_QC);
  u16*   KC    = (u16*)(W + OFF_KC);
  u16*   VC    = (u16*)(W + OFF_VC);
  u16*   WT1   = (u16*)(W + OFF_WT1);
  u16*   WT2   = (u16*)(W + OFF_WT2);
  u16*   VCM   = (u16*)(W + OFF_VCM);
  u16*   F2CM  = VCM;                     // time-shared
  float* CEN   = (float*)(W + OFF_CEN);
  u16*   CATT  = (u16*)(W + OFF_CATT);
  float* OUT   = (float*)d_out;

  // zero padded tensors (ring + guards must be 0 for shifted conv reads)
  hipMemsetAsync(XPM,  0, (size_t)2*(PP+2*GUARD)*CIN*2, stream);
  hipMemsetAsync(SAPM, 0, (size_t)2*(PP+2*GUARD)*CI*2,  stream);
  hipMemsetAsync(SCPM, 0, (size_t)2*(PP+2*GUARD)*CI*2,  stream);

  k_padx<<<dim3(57,32,2),256,0,stream>>>(x, XPM);

  // conv s0 + c0 fused (N-concat): [feat1|feat2] = bn_relu(conv3(x, [w_s0;w_c0]))
  k_wt<<<(512*2048)/256,256,0,stream>>>(w_s0, WTT, 2048);
  k_wt<<<(512*2048)/256,256,0,stream>>>(w_c0, WTT + (size_t)512*9*2048, 2048);
  GArgs a{};
  a.A = XPM + (size_t)GUARD*CIN; a.B = WTT; a.Cb = F1; a.Cb2 = F2;
  a.bn = bn_s0; a.bn2 = bn_c0;
  a.sA = (long)(PP+2*GUARD)*CIN; a.sB = 0; a.sC = (long)PP*CI;
  a.M = PP; a.N = 1024; a.nsplit = 512; a.KT = 576; a.ktps = 64;
  a.lda = CIN; a.ldb = 9*2048; a.ldc = CI; a.Mclamp = PP-1; a.Nclamp = 1023;
  k_gemm<0,true,true,false><<<dim3(32,8,2),256,0,stream>>>(a);

  // bf16 copies of 1x1 weights (concat [wq;wk;wv] = 640x512)
  k_cvt<<<(64*512+255)/256,256,0,stream>>>(wq, WQB, 64*512);
  k_cvt<<<(64*512+255)/256,256,0,stream>>>(wk, WKB, 64*512);
  k_cvt<<<(512*512+255)/256,256,0,stream>>>(wv, WVB, 512*512);

  // q,k,v in one GEMM (N=640)
  GArgs q{};
  q.A = F1; q.sA = (long)PP*CI; q.lda = CI;
  q.M = PP; q.Mclamp = PP-1; q.KT = 16; q.ktps = 16;
  q.B = WQB; q.sB = 0; q.ldb = CI; q.N = 640; q.Nclamp = 639;
  q.Cb = QC; q.Cb2 = KC; q.Cb3 = VC; q.bias = bq; q.bias2 = bk; q.bias3 = bv;
  k_gemm<6,false,false,false><<<dim3(32,5,2),256,0,stream>>>(q);

  k_to_cm<false><<<dim3(57, CI/64, 2),256,0,stream>>>(VC, VCM, (long)NPIX*CI, (long)CI*NK);

  // position attention, per batch: E (chunked) -> softmax -> PV
  for(int bb=0; bb<2; ++bb){
    for(int c0=0; c0<NPIX; c0+=1024){
      int Mc = NPIX - c0; if (Mc > 1024) Mc = 1024;
      GArgs e{};
      e.A = QC + (size_t)bb*NPIX*CQ + (size_t)c0*CQ;
      e.B = KC + (size_t)bb*NPIX*CQ;
      e.Cf = EB;
      e.M = Mc; e.N = NPIX; e.KT = 2; e.ktps = 2;
      e.lda = CQ; e.ldb = CQ; e.ldc = NPIX;
      e.Mclamp = Mc-1; e.Nclamp = NPIX-1;
      e.dR = dd + (size_t)bb*NPIX + c0; e.dC = dd + (size_t)bb*NPIX; e.lambp = lam;
      k_gemm<2,false,false,false><<<dim3((Mc+127)/128, 29, 1),256,0,stream>>>(e);
      k_softmax<<<Mc,256,0,stream>>>(EB, PB, c0);
    }
    GArgs p{};
    p.A = PB; p.B = VCM + (size_t)bb*CI*NK;
    p.Cb = SAPM + (size_t)bb*(PP+2*GUARD)*CI + (size_t)GUARD*CI;
    p.resid = F1 + (size_t)bb*PP*CI;
    p.gamma = gsa;
    p.M = NPIX; p.N = CI; p.KT = NK/32; p.ktps = NK/32;
    p.lda = NK; p.ldb = NK; p.ldc = CI;
    p.Mclamp = NPIX-1; p.Nclamp = CI-1;
    k_gemm<4,false,false,false><<<dim3(29, 4, 1),256,0,stream>>>(p);
  }

  // channel attention
  k_to_cm<true><<<dim3(57, CI/64, 2),256,0,stream>>>(F2, F2CM, (long)PP*CI, (long)CI*NK);
  GArgs c{};
  c.A = F2CM; c.B = F2CM; c.Cf = CEN;
  c.sA = (long)CI*NK; c.sB = (long)CI*NK; c.sC = (long)CI*CI;
  c.M = CI; c.N = CI; c.KT = NK/32; c.ktps = NK/32;
  c.lda = NK; c.ldb = NK; c.ldc = CI; c.Mclamp = CI-1; c.Nclamp = CI-1;
  k_gemm<3,false,false,false><<<dim3(4, 4, 2),256,0,stream>>>(c);
  k_csoftmax<<<dim3(CI,2),256,0,stream>>>(CEN, CATT);
  GArgs s{};
  s.A = F2; s.B = CATT;
  s.Cb = SCPM + (size_t)GUARD*CI;
  s.resid = F2; s.gamma = gsc;
  s.sA = (long)PP*CI; s.sB = (long)CI*CI; s.sC = (long)(PP+2*GUARD)*CI; s.sres = (long)PP*CI;
  s.M = PP; s.N = CI; s.KT = 16; s.ktps = 16;
  s.lda = CI; s.ldb = CI; s.ldc = CI; s.Mclamp = PP-1; s.Nclamp = CI-1;
  k_gemm<5,false,false,false><<<dim3(32, 4, 2),256,0,stream>>>(s);

  // post convs s1 + c1 fused (DUALZ)
  k_wt<<<(512*512)/256,256,0,stream>>>(w_s1, WT1, 512);
  k_wt<<<(512*512)/256,256,0,stream>>>(w_c1, WT2, 512);
  GArgs t{};
  t.A = SAPM + (size_t)GUARD*CI; t.A2 = SCPM + (size_t)GUARD*CI;
  t.B = WT1; t.B2 = WT2;
  t.Cb = SACONV; t.Cb2 = SCCONV; t.bn = bn_s1; t.bn2 = bn_c1;
  t.sA = (long)(PP+2*GUARD)*CI; t.sB = 0; t.sC = (long)PP*CI;
  t.M = PP; t.N = CI; t.KT = 144; t.ktps = 16;
  t.lda = CI; t.ldb = 9*512; t.ldc = CI; t.Mclamp = PP-1; t.Nclamp = CI-1;
  k_gemm<0,true,false,true><<<dim3(32,4,4),256,0,stream>>>(t);

  // fused heads
  k_head<<<dim3(57,2),256,0,stream>>>(SACONV, SCCONV, w6,b6,w7,b7,w8,b8, OUT);
}

// Round 4
// 953.314 us; speedup vs baseline: 2.0209x; 1.2932x over previous
//
#include <hip/hip_runtime.h>
#include <stdint.h>

#define DI __device__ __forceinline__

typedef unsigned short u16;
typedef unsigned int u32;
typedef __attribute__((ext_vector_type(8))) short short8;
typedef __attribute__((ext_vector_type(4))) float floatx4;

// ---------------- geometry ----------------
constexpr int NPIX = 3600;   // 60*60
constexpr int NK   = 3712;   // 3600 padded to multiple of 128 (zero tail)
constexpr int PP   = 4096;   // 64*64 padded pixel grid (image at [2..61]^2)
constexpr int GUARD= 128;    // guard rows on padded-pixel tensors (shifted reads)
constexpr int CIN  = 2048, CI = 512, CQ = 64;

// ---------------- ws layout (bytes) ----------------
// R1 time-shared: XPM (convs) -> EBUF(+SAF)/PBUF (attention) -> SACONV/SCCONV (tail)
constexpr size_t OFF_XPM    = 0;                       // 2*4352*2048*2 = 35,651,584
constexpr size_t OFF_EBUF   = 0;                       // 1024*3600*4   = 14,745,600 (also SAF 3600*512*4)
constexpr size_t OFF_PBUF   = 14745600;                // 3600*3712*2   = 26,726,400 -> ends 41,472,000
constexpr size_t OFF_SACONV = 0;                       // 4096*512*2    = 4,194,304*2b = 8,388,608
constexpr size_t OFF_SCCONV = 8388608;
constexpr size_t R1_END     = 42812416;
constexpr size_t OFF_FEAT1  = R1_END;                  // 8,388,608
constexpr size_t OFF_FEAT2  = OFF_FEAT1 + 8388608;
constexpr size_t OFF_SAPM   = OFF_FEAT2 + 8388608;     // 8,912,896
constexpr size_t OFF_SCPM   = OFF_SAPM + 8912896;
constexpr size_t OFF_W      = OFF_SCPM + 8912896;      // big region, 37,748,736 (WTT 1024x18432)
// inside W (time-shared with WTT / each other):
constexpr size_t OFF_WQB = OFF_W;                      // 64*512*2
constexpr size_t OFF_WKB = OFF_W + 65536;
constexpr size_t OFF_WVB = OFF_W + 131072;             // 512*512*2
constexpr size_t OFF_QC  = OFF_W + 655360;             // 2*3600*64*2
constexpr size_t OFF_KC  = OFF_W + 1576960;
constexpr size_t OFF_VC  = OFF_W + 2498560;            // 2*3600*512*2 -> ends +9,871,360
constexpr size_t OFF_WT1 = OFF_W;                      // 512*4608*2 (s1) — QC/KC/VC dead by then
constexpr size_t OFF_WT2 = OFF_W + 4718592;            // 512*4608*2 (c1)
constexpr size_t OFF_VCM = OFF_W + 9871360;            // 2*512*3712*2 = 7,602,176 (shared w/ F2CM)
constexpr size_t OFF_CEN = OFF_W + 17473536;           // 2*512*512*4 = 2,097,152
constexpr size_t OFF_CATT= OFF_W + 19570688;           // 2*512*512*2 = 1,048,576 -> ends +20,619,264
constexpr size_t WS_NEED = OFF_W + 37748736;           // 115,164,160 (same as proven round 3)

// ---------------- helpers ----------------
DI float b2f(u16 s){ u32 u = ((u32)s)<<16; float f; __builtin_memcpy(&f,&u,4); return f; }
DI u16 f2b(float f){ u32 u; __builtin_memcpy(&u,&f,4); u32 r=(u+0x7fffu+((u>>16)&1u))>>16; return (u16)r; }
DI int pad_of(int n){ int y=n/60, x=n-y*60; return ((y+2)<<6)+x+2; }
DI bool interior(int p){ int py=p>>6, px=p&63; return (py>=2)&&(py<62)&&(px>=2)&&(px<62); }
DI int compact_of(int p){ return ((p>>6)-2)*60 + (p&63) - 2; }
DI void gll16(const void* g, void* l){
  __builtin_amdgcn_global_load_lds((const __attribute__((address_space(1))) void*)g,
                                   (__attribute__((address_space(3))) void*)l, 16, 0, 0);
}
DI float wred_max(float v){
#pragma unroll
  for(int m=32;m;m>>=1) v=fmaxf(v,__shfl_xor(v,m,64));
  return v;
}
DI float wred_min(float v){
#pragma unroll
  for(int m=32;m;m>>=1) v=fminf(v,__shfl_xor(v,m,64));
  return v;
}
DI float wred_sum(float v){
#pragma unroll
  for(int m=32;m;m>>=1) v+=__shfl_xor(v,m,64);
  return v;
}

// ---------------- NT GEMM: C[M,N] = sum_k A[m,k]*B[n,k] (A,B bf16) ----------------
// MODE 0: conv epilogue relu(bn(acc)) -> bf16, interior rows. NCAT: gc>=nsplit -> {Cb2,bn2}.
//         DUALZ: bz>>1 selects {A2,B2,Cb2,bn2}, bz&1 = batch.
// MODE 2: energy acc+lam*(dR-dC)^2 -> f32
// MODE 3: plain f32 (SPLITK: atomicAdd into zeroed Cf)
// MODE 5: sc: gamma*acc+resid[gr,gc] -> bf16, interior gr
// MODE 6: qkv concat: gc<64 -> QC(+bq), <128 -> KC(+bk), else VC(+bv); compact rows
struct GArgs {
  const u16 *A, *A2, *B, *B2; u16 *Cb, *Cb2, *Cb3; float* Cf;
  const u16* resid;
  const float *bn, *bn2, *bias, *bias2, *bias3, *gamma, *lambp, *dR, *dC;
  long sA, sB, sC, sres;
  int M, N, KT, ktps, lda, ldb, ldc, Mclamp, Nclamp, nsplit, ksplit, kps;
};

template<int MODE, bool SHIFT, bool NCAT, bool DUALZ, int U, bool SPLITK>
__global__ __launch_bounds__(256) void k_gemm(GArgs g){
  __shared__ alignas(16) short As[U*4096];
  __shared__ alignas(16) short Bs[U*4096];
  const int bz = blockIdx.z;
  const int sel = DUALZ ? (bz>>1) : 0;
  int bt  = DUALZ ? (bz&1)  : bz;
  int slice = 0;
  if constexpr(SPLITK){ bt = bz / g.ksplit; slice = bz - bt*g.ksplit; }
  const u16* Ab = ((DUALZ && sel) ? g.A2 : g.A) + (long)bt*g.sA;
  const u16* Bb = ((DUALZ && sel) ? g.B2 : g.B) + (long)bt*g.sB;
  const int m0 = blockIdx.x*128, n0 = blockIdx.y*128;
  const int tid = threadIdx.x, wid = tid>>6, lane = tid&63;
  const int wr = wid>>1, wc = wid&1;
  const int fr = lane&15, fq = lane>>4;
  const int srow = lane>>2;
  const int swz = ((lane&3) ^ ((lane>>3)&3)) << 3;   // swizzled 8-short slot within 32-short row

  long raB[2], rbB[2];
#pragma unroll
  for(int h=0;h<2;h++){
    long ra = m0 + wid*32 + h*16 + srow;
    if (!SHIFT) ra = (ra > g.Mclamp) ? (long)g.Mclamp : ra;
    raB[h] = ra*(long)g.lda + swz;
    long rb = n0 + wid*32 + h*16 + srow;
    rb = (rb > g.Nclamp) ? (long)g.Nclamp : rb;
    rbB[h] = rb*(long)g.ldb + swz;
  }
  const int ldsOff[2] = { (wid*32)*64, (wid*32+16)*64 };   // byte offsets within one buffer
  const int rswz = (fq ^ ((fr>>1)&3)) << 3;                // read-side slot (same involution)
  const int aRdO = (wr*64+fr)*32 + rswz;                   // shorts, within one buffer
  const int bRdO = (wc*64+fr)*32 + rswz;

  floatx4 acc[4][4];
#pragma unroll
  for(int i=0;i<4;i++)
#pragma unroll
    for(int j=0;j<4;j++)
#pragma unroll
      for(int e=0;e<4;e++) acc[i][j][e]=0.f;

  if constexpr(SHIFT){
    const int KB = g.ktps;
    for(int s=0; s<9; ++s){
      const long aoff = (long)((s/3)*64 + (s-(s/3)*3) - 65)*g.lda; // (ky-1)*64+(kx-1)
      const long boff = (long)s*KB*32;
      for(int kb=0; kb<KB; kb+=U){
        __syncthreads();
#pragma unroll
        for(int u=0;u<U;++u){
          const int ko = (kb+u)*32;
#pragma unroll
          for(int h=0;h<2;h++){
            gll16(Ab + raB[h] + aoff + ko, (char*)As + u*8192 + ldsOff[h]);
            gll16(Bb + rbB[h] + boff + ko, (char*)Bs + u*8192 + ldsOff[h]);
          }
        }
        __syncthreads();
#pragma unroll
        for(int u=0;u<U;++u){
          short8 af[4], bfv[4];
#pragma unroll
          for(int mi=0;mi<4;mi++) af[mi]  = *(const short8*)(As + u*4096 + aRdO + mi*512);
#pragma unroll
          for(int ni=0;ni<4;ni++) bfv[ni] = *(const short8*)(Bs + u*4096 + bRdO + ni*512);
#pragma unroll
          for(int mi=0;mi<4;mi++)
#pragma unroll
            for(int ni=0;ni<4;ni++)
              acc[mi][ni] = __builtin_amdgcn_mfma_f32_16x16x32_bf16(af[mi], bfv[ni], acc[mi][ni], 0,0,0);
        }
      }
    }
  } else {
    int kt0 = 0, ktN = g.KT;
    if constexpr(SPLITK){ kt0 = slice*g.kps; ktN = min(g.KT, kt0+g.kps); }
    for(int kt=kt0; kt<ktN; kt+=U){
      __syncthreads();
#pragma unroll
      for(int u=0;u<U;++u){
        if (kt+u < ktN){
          const int ko = (kt+u)*32;
#pragma unroll
          for(int h=0;h<2;h++){
            gll16(Ab + raB[h] + ko, (char*)As + u*8192 + ldsOff[h]);
            gll16(Bb + rbB[h] + ko, (char*)Bs + u*8192 + ldsOff[h]);
          }
        }
      }
      __syncthreads();
#pragma unroll
      for(int u=0;u<U;++u){
        if (kt+u < ktN){
          short8 af[4], bfv[4];
#pragma unroll
          for(int mi=0;mi<4;mi++) af[mi]  = *(const short8*)(As + u*4096 + aRdO + mi*512);
#pragma unroll
          for(int ni=0;ni<4;ni++) bfv[ni] = *(const short8*)(Bs + u*4096 + bRdO + ni*512);
#pragma unroll
          for(int mi=0;mi<4;mi++)
#pragma unroll
            for(int ni=0;ni<4;ni++)
              acc[mi][ni] = __builtin_amdgcn_mfma_f32_16x16x32_bf16(af[mi], bfv[ni], acc[mi][ni], 0,0,0);
        }
      }
    }
  }

  float* Cf = (MODE==2||MODE==3) ? g.Cf + (long)bt*g.sC : nullptr;
  const u16* Rb = (MODE==5) ? g.resid + (long)bt*g.sres : nullptr;
  float lamv=0.f, gamv=0.f;
  if constexpr(MODE==2) lamv = *g.lambp;
  if constexpr(MODE==5) gamv = *g.gamma;

#pragma unroll
  for(int ni=0;ni<4;ni++){
    const int gc = n0 + wc*64 + ni*16 + fr;
    if (gc >= g.N) continue;
    if constexpr(MODE==0){
      const float* bnP = g.bn; u16* CbP = g.Cb; int oc = gc;
      if constexpr(DUALZ){ if (sel){ bnP = g.bn2; CbP = g.Cb2; } }
      if constexpr(NCAT){ if (gc >= g.nsplit){ bnP = g.bn2; CbP = g.Cb2; oc = gc - g.nsplit; } }
      CbP += (long)bt*g.sC;
      const float s_=bnP[oc], bb=bnP[CI+oc], mm=bnP[2*CI+oc], vv=bnP[3*CI+oc];
      const float cA = s_*rsqrtf(vv+1e-5f), cB = bb - cA*mm;
#pragma unroll
      for(int mi=0;mi<4;mi++)
#pragma unroll
        for(int j=0;j<4;j++){
          const int gr = m0 + wr*64 + mi*16 + fq*4 + j;
          if (interior(gr)) CbP[(size_t)gr*g.ldc + oc] = f2b(fmaxf(cA*acc[mi][ni][j]+cB, 0.f));
        }
    } else if constexpr(MODE==6){
      u16* dst; int col, ld; float bs;
      if (gc < 64){ dst = g.Cb  + (long)bt*((long)NPIX*CQ); col=gc;     ld=CQ; bs=g.bias[gc]; }
      else if (gc < 128){ dst = g.Cb2 + (long)bt*((long)NPIX*CQ); col=gc-64; ld=CQ; bs=g.bias2[gc-64]; }
      else { dst = g.Cb3 + (long)bt*((long)NPIX*CI); col=gc-128; ld=CI; bs=g.bias3[gc-128]; }
#pragma unroll
      for(int mi=0;mi<4;mi++)
#pragma unroll
        for(int j=0;j<4;j++){
          const int gr = m0 + wr*64 + mi*16 + fq*4 + j;
          if (interior(gr)) dst[(size_t)compact_of(gr)*ld + col] = f2b(acc[mi][ni][j] + bs);
        }
    } else if constexpr(MODE==2){
      const float dc = g.dC[gc];
#pragma unroll
      for(int mi=0;mi<4;mi++)
#pragma unroll
        for(int j=0;j<4;j++){
          const int gr = m0 + wr*64 + mi*16 + fq*4 + j;
          if (gr < g.M){ const float t=g.dR[gr]-dc; Cf[(size_t)gr*g.ldc + gc] = acc[mi][ni][j] + lamv*t*t; }
        }
    } else if constexpr(MODE==3){
#pragma unroll
      for(int mi=0;mi<4;mi++)
#pragma unroll
        for(int j=0;j<4;j++){
          const int gr = m0 + wr*64 + mi*16 + fq*4 + j;
          if (gr < g.M){
            if constexpr(SPLITK) atomicAdd(&Cf[(size_t)gr*g.ldc + gc], acc[mi][ni][j]);
            else Cf[(size_t)gr*g.ldc + gc] = acc[mi][ni][j];
          }
        }
    } else if constexpr(MODE==5){
      u16* CbP = g.Cb + (long)bt*g.sC;
#pragma unroll
      for(int mi=0;mi<4;mi++)
#pragma unroll
        for(int j=0;j<4;j++){
          const int gr = m0 + wr*64 + mi*16 + fq*4 + j;
          if (interior(gr)){ const size_t o=(size_t)gr*g.ldc + gc; CbP[o] = f2b(gamv*acc[mi][ni][j] + b2f(Rb[o])); }
        }
    }
  }
}

// ---------------- x f32 [B,2048,3600] -> padded pixel-major bf16 [B][4352][2048] ----------------
__global__ __launch_bounds__(256) void k_padx(const float* __restrict__ x, u16* __restrict__ xpm){
  __shared__ alignas(16) u16 t[64][72];
  const int n0 = blockIdx.x*64, c0 = blockIdx.y*64, b = blockIdx.z;
  const float* xb = x + (size_t)b*CIN*NPIX;
  u16* ob = xpm + (size_t)b*(PP+2*GUARD)*CIN + (size_t)GUARD*CIN;
  const int tid = threadIdx.x;
#pragma unroll
  for(int pass=0; pass<2; ++pass){
    const int cl = pass*32 + (tid>>3);
    const int nn = (tid&7)*8;
    const int n = n0 + nn;
    const float* src = xb + (size_t)(c0+cl)*NPIX + n;
    u16 r[8];
    if (n + 7 < NPIX){
      const float4 v0 = *(const float4*)src;
      const float4 v1 = *(const float4*)(src+4);
      r[0]=f2b(v0.x); r[1]=f2b(v0.y); r[2]=f2b(v0.z); r[3]=f2b(v0.w);
      r[4]=f2b(v1.x); r[5]=f2b(v1.y); r[6]=f2b(v1.z); r[7]=f2b(v1.w);
    } else {
#pragma unroll
      for(int j=0;j<8;j++){ const int nj=n+j; r[j] = (nj<NPIX)? f2b(src[j]) : (u16)0; }
    }
    __builtin_memcpy(&t[cl][nn], r, 16);
  }
  __syncthreads();
#pragma unroll
  for(int pass=0; pass<2; ++pass){
    const int nl = pass*32 + (tid>>3);
    const int cc = (tid&7)*8;
    const int n = n0 + nl;
    if (n < NPIX){
      u16 v[8];
#pragma unroll
      for(int j=0;j<8;j++) v[j] = t[cc+j][nl];
      uint4 vv; __builtin_memcpy(&vv, v, 16);
      *(uint4*)(ob + (size_t)pad_of(n)*CIN + c0 + cc) = vv;
    }
  }
}

// ---------------- bf16 [rows, 512] pixel-major -> [512, NK] channel-major (zero tail) ----------------
template<bool PADIN>
__global__ __launch_bounds__(256) void k_to_cm(const u16* __restrict__ in, u16* __restrict__ out,
                                               long sIn, long sOut){
  __shared__ alignas(16) u16 t[64][72];
  const int n0 = blockIdx.x*64, c0 = blockIdx.y*64, b = blockIdx.z;
  const u16* ib = in + (size_t)b*sIn;
  u16* ob = out + (size_t)b*sOut;
  const int tid = threadIdx.x;
#pragma unroll
  for(int pass=0; pass<2; ++pass){
    const int nl = pass*32 + (tid>>3);
    const int cc = (tid&7)*8;
    const int n = n0 + nl;
    uint4 v = {0,0,0,0};
    if (n < NPIX){
      const int r = PADIN ? pad_of(n) : n;
      v = *(const uint4*)(ib + (size_t)r*CI + c0 + cc);
    }
    *(uint4*)&t[nl][cc] = v;
  }
  __syncthreads();
#pragma unroll
  for(int pass=0; pass<2; ++pass){
    const int cl = pass*32 + (tid>>3);
    const int nn = (tid&7)*8;
    const int n = n0 + nn;
    if (n < NK){
      u16 v[8];
#pragma unroll
      for(int j=0;j<8;j++) v[j] = t[nn+j][cl];
      uint4 vv; __builtin_memcpy(&vv, v, 16);
      *(uint4*)(ob + (size_t)(c0+cl)*NK + n) = vv;
    }
  }
}

// ---------------- w f32 [O,Kc,3,3] -> Wt bf16 [O, 9*Kc], Wt[o, s*Kc+i] = w[o,i,s] ----------------
__global__ __launch_bounds__(256) void k_wt(const float* __restrict__ w, u16* __restrict__ wt, int Kc){
  const int idx = blockIdx.x*256 + threadIdx.x;
  const int o = idx / Kc, i = idx - o*Kc;
  u16 v[9];
#pragma unroll
  for(int s=0;s<9;s++) v[s] = f2b(w[(size_t)idx*9 + s]);
#pragma unroll
  for(int s=0;s<9;s++) wt[(size_t)o*9*Kc + (size_t)s*Kc + i] = v[s];
}

// ---------------- f32 -> bf16 elementwise ----------------
__global__ __launch_bounds__(256) void k_cvt(const float* __restrict__ src, u16* __restrict__ dst, int n){
  const int i = blockIdx.x*256 + threadIdx.x;
  if (i < n) dst[i] = f2b(src[i]);
}

// ---------------- row softmax: E[r, 0..3599] f32 -> P[(c0+r), 0..NK-1] bf16 ----------------
__global__ __launch_bounds__(256) void k_softmax(const float* __restrict__ E, u16* __restrict__ P, int c0){
  __shared__ float row[NK];
  __shared__ float red[8];
  const int r = blockIdx.x, tid = threadIdx.x;
  const float* e = E + (size_t)r*NPIX;
  float lmax = -3e38f;
  for(int i=tid;i<NK;i+=256){
    const float v = (i<NPIX)? e[i] : -3e38f;
    row[i]=v; lmax=fmaxf(lmax,v);
  }
  lmax = wred_max(lmax);
  if((tid&63)==0) red[tid>>6]=lmax;
  __syncthreads();
  const float m = fmaxf(fmaxf(red[0],red[1]),fmaxf(red[2],red[3]));
  float ls=0.f;
  for(int i=tid;i<NK;i+=256){
    const float v=__expf(row[i]-m);
    row[i]=v; ls+=v;
  }
  ls = wred_sum(ls);
  if((tid&63)==0) red[4+(tid>>6)]=ls;
  __syncthreads();
  const float inv = 1.f/(red[4]+red[5]+red[6]+red[7]);
  u16* po = P + (size_t)(c0+r)*NK;
  for(int i=tid;i<NK;i+=256) po[i]=f2b(row[i]*inv);
}

// ---------------- channel softmax ----------------
__global__ __launch_bounds__(256) void k_csoftmax(const float* __restrict__ cen, u16* __restrict__ catt){
  const int c = blockIdx.x, b = blockIdx.y, tid = threadIdx.x;
  const float* e = cen + ((size_t)b*CI + c)*CI;
  u16* o = catt + ((size_t)b*CI + c)*CI;
  __shared__ float red[8];
  const float a0 = e[tid], a1 = e[tid+256];
  float lmin = fminf(a0,a1);
  lmin = wred_min(lmin);
  if((tid&63)==0) red[tid>>6]=lmin;
  __syncthreads();
  const float m0 = fminf(fminf(red[0],red[1]),fminf(red[2],red[3]));
  const float x0 = __expf(m0-a0), x1 = __expf(m0-a1);
  float ls = x0+x1;
  ls = wred_sum(ls);
  if((tid&63)==0) red[4+(tid>>6)]=ls;
  __syncthreads();
  const float inv = 1.f/(red[4]+red[5]+red[6]+red[7]);
  o[tid] = f2b(x0*inv); o[tid+256] = f2b(x1*inv);
}

// ---------------- PV epilogue: SAPM[pad(n),c] = gamma*SAF[n,c] + F1[pad(n),c] ----------------
__global__ __launch_bounds__(256) void k_pv_ep(const float* __restrict__ saf, const u16* __restrict__ f1,
                                               u16* __restrict__ sapm, const float* __restrict__ gamma){
  const int idx = blockIdx.x*256 + threadIdx.x;   // 230400 threads, 8 elems each
  const int n = idx >> 6, c = (idx & 63) * 8;
  const float gam = *gamma;
  const int p = pad_of(n);
  const float4 v0 = *(const float4*)(saf + (size_t)n*CI + c);
  const float4 v1 = *(const float4*)(saf + (size_t)n*CI + c + 4);
  const uint4 rv = *(const uint4*)(f1 + (size_t)p*CI + c);
  const u16* rp = (const u16*)&rv;
  u16 o[8];
  o[0]=f2b(gam*v0.x + b2f(rp[0])); o[1]=f2b(gam*v0.y + b2f(rp[1]));
  o[2]=f2b(gam*v0.z + b2f(rp[2])); o[3]=f2b(gam*v0.w + b2f(rp[3]));
  o[4]=f2b(gam*v1.x + b2f(rp[4])); o[5]=f2b(gam*v1.y + b2f(rp[5]));
  o[6]=f2b(gam*v1.z + b2f(rp[6])); o[7]=f2b(gam*v1.w + b2f(rp[7]));
  uint4 ov; __builtin_memcpy(&ov, o, 16);
  *(uint4*)(sapm + (size_t)p*CI + c) = ov;
}

// ---------------- fused 1x1 head ----------------
__global__ __launch_bounds__(256) void k_head(const u16* __restrict__ sa, const u16* __restrict__ sc,
    const float* __restrict__ w6, const float* __restrict__ b6,
    const float* __restrict__ w7, const float* __restrict__ b7,
    const float* __restrict__ w8, const float* __restrict__ b8,
    float* __restrict__ out){
  __shared__ float fa[64][65], fb[64][65];
  __shared__ float wf[3][40][64];
  const int n0 = blockIdx.x*64, b = blockIdx.y;
  const u16* sab = sa + (size_t)b*PP*CI;
  const u16* scb = sc + (size_t)b*PP*CI;
  const int tid = threadIdx.x;
  const int px = tid & 63, og = tid >> 6;
  float a6[10], a7[10], a8[10];
#pragma unroll
  for(int i=0;i<10;i++){ a6[i]=0.f; a7[i]=0.f; a8[i]=0.f; }
  for(int cc0=0; cc0<CI; cc0+=64){
    __syncthreads();
#pragma unroll
    for(int pass=0; pass<2; ++pass){
      const int rl = pass*32 + (tid>>3);
      const int cq = (tid&7)*8;
      const int n = n0 + rl;
      const int prow = pad_of(n < NPIX ? n : NPIX-1);
      const uint4 va = *(const uint4*)(sab + (size_t)prow*CI + cc0 + cq);
      const uint4 vb = *(const uint4*)(scb + (size_t)prow*CI + cc0 + cq);
      const u16* pa = (const u16*)&va; const u16* pb = (const u16*)&vb;
#pragma unroll
      for(int j=0;j<8;j++){ fa[rl][cq+j] = b2f(pa[j]); fb[rl][cq+j] = b2f(pb[j]); }
    }
    for(int i=tid; i<40*64; i+=256){
      const int o = i>>6, c = i&63;
      wf[0][o][c] = w6[(size_t)o*CI + cc0 + c];
      wf[1][o][c] = w7[(size_t)o*CI + cc0 + c];
      wf[2][o][c] = w8[(size_t)o*CI + cc0 + c];
    }
    __syncthreads();
    for(int cl=0; cl<64; ++cl){
      const float va = fa[px][cl], vb = fb[px][cl], vs = va+vb;
#pragma unroll
      for(int oo=0;oo<10;oo++){
        const int o = og*10+oo;
        a6[oo] += wf[0][o][cl]*va;
        a7[oo] += wf[1][o][cl]*vb;
        a8[oo] += wf[2][o][cl]*vs;
      }
    }
  }
  const int n = n0 + px;
  if (n < NPIX){
#pragma unroll
    for(int oo=0;oo<10;oo++){
      const int o = og*10+oo;
      out[(size_t)b*144000 + (size_t)o*NPIX + n]          = a8[oo] + b8[o]; // sasc
      out[288000 + (size_t)b*144000 + (size_t)o*NPIX + n] = a6[oo] + b6[o]; // sa_output
      out[576000 + (size_t)b*144000 + (size_t)o*NPIX + n] = a7[oo] + b7[o]; // sc_output
    }
  }
}

// ---------------- launch ----------------
extern "C" void kernel_launch(void* const* d_in, const int* in_sizes, int n_in,
                              void* d_out, int out_size, void* d_ws, size_t ws_size,
                              hipStream_t stream){
  (void)in_sizes; (void)n_in; (void)out_size;
  if (ws_size < WS_NEED) return;

  const float* x    = (const float*)d_in[0];
  const float* dd   = (const float*)d_in[1];
  const float* w_s0 = (const float*)d_in[2];
  const float* bn_s0= (const float*)d_in[3];
  const float* wq   = (const float*)d_in[4];
  const float* bq   = (const float*)d_in[5];
  const float* wk   = (const float*)d_in[6];
  const float* bk   = (const float*)d_in[7];
  const float* wv   = (const float*)d_in[8];
  const float* bv   = (const float*)d_in[9];
  const float* gsa  = (const float*)d_in[10];
  const float* lam  = (const float*)d_in[11];
  const float* w_s1 = (const float*)d_in[12];
  const float* bn_s1= (const float*)d_in[13];
  const float* w6   = (const float*)d_in[14];
  const float* b6   = (const float*)d_in[15];
  const float* w_c0 = (const float*)d_in[16];
  const float* bn_c0= (const float*)d_in[17];
  const float* gsc  = (const float*)d_in[18];
  const float* w_c1 = (const float*)d_in[19];
  const float* bn_c1= (const float*)d_in[20];
  const float* w7   = (const float*)d_in[21];
  const float* b7   = (const float*)d_in[22];
  const float* w8   = (const float*)d_in[23];
  const float* b8   = (const float*)d_in[24];

  char* W = (char*)d_ws;
  u16*   XPM   = (u16*)(W + OFF_XPM);
  float* EB    = (float*)(W + OFF_EBUF);
  float* SAF   = (float*)(W + OFF_EBUF);   // time-shared with EB
  u16*   PB    = (u16*)(W + OFF_PBUF);
  u16*   SACONV= (u16*)(W + OFF_SACONV);
  u16*   SCCONV= (u16*)(W + OFF_SCCONV);
  u16*   F1    = (u16*)(W + OFF_FEAT1);
  u16*   F2    = (u16*)(W + OFF_FEAT2);
  u16*   SAPM  = (u16*)(W + OFF_SAPM);
  u16*   SCPM  = (u16*)(W + OFF_SCPM);
  u16*   WTT   = (u16*)(W + OFF_W);
  u16*   WQB   = (u16*)(W + OFF_WQB);
  u16*   WKB   = (u16*)(W + OFF_WKB);
  u16*   WVB   = (u16*)(W + OFF_WVB);
  u16*   QC    = (u16*)(W + OFF_QC);
  u16*   KC    = (u16*)(W + OFF_KC);
  u16*   VC    = (u16*)(W + OFF_VC);
  u16*   WT1   = (u16*)(W + OFF_WT1);
  u16*   WT2   = (u16*)(W + OFF_WT2);
  u16*   VCM   = (u16*)(W + OFF_VCM);
  u16*   F2CM  = VCM;                     // time-shared
  float* CEN   = (float*)(W + OFF_CEN);
  u16*   CATT  = (u16*)(W + OFF_CATT);
  float* OUT   = (float*)d_out;

  // zero padded tensors (ring + guards must be 0 for shifted conv reads)
  hipMemsetAsync(XPM,  0, (size_t)2*(PP+2*GUARD)*CIN*2, stream);
  hipMemsetAsync(SAPM, 0, (size_t)2*(PP+2*GUARD)*CI*2,  stream);
  hipMemsetAsync(SCPM, 0, (size_t)2*(PP+2*GUARD)*CI*2,  stream);

  k_padx<<<dim3(57,32,2),256,0,stream>>>(x, XPM);

  // conv s0 + c0 fused (N-concat), U=4 (BK=128)
  k_wt<<<(512*2048)/256,256,0,stream>>>(w_s0, WTT, 2048);
  k_wt<<<(512*2048)/256,256,0,stream>>>(w_c0, WTT + (size_t)512*9*2048, 2048);
  GArgs a{};
  a.A = XPM + (size_t)GUARD*CIN; a.B = WTT; a.Cb = F1; a.Cb2 = F2;
  a.bn = bn_s0; a.bn2 = bn_c0;
  a.sA = (long)(PP+2*GUARD)*CIN; a.sB = 0; a.sC = (long)PP*CI;
  a.M = PP; a.N = 1024; a.nsplit = 512; a.KT = 576; a.ktps = 64;
  a.lda = CIN; a.ldb = 9*2048; a.ldc = CI; a.Mclamp = PP-1; a.Nclamp = 1023;
  k_gemm<0,true,true,false,4,false><<<dim3(32,8,2),256,0,stream>>>(a);

  // bf16 copies of 1x1 weights (concat [wq;wk;wv] = 640x512)
  k_cvt<<<(64*512+255)/256,256,0,stream>>>(wq, WQB, 64*512);
  k_cvt<<<(64*512+255)/256,256,0,stream>>>(wk, WKB, 64*512);
  k_cvt<<<(512*512+255)/256,256,0,stream>>>(wv, WVB, 512*512);

  // q,k,v in one GEMM (N=640), U=4
  GArgs q{};
  q.A = F1; q.sA = (long)PP*CI; q.lda = CI;
  q.M = PP; q.Mclamp = PP-1; q.KT = 16; q.ktps = 16;
  q.B = WQB; q.sB = 0; q.ldb = CI; q.N = 640; q.Nclamp = 639;
  q.Cb = QC; q.Cb2 = KC; q.Cb3 = VC; q.bias = bq; q.bias2 = bk; q.bias3 = bv;
  k_gemm<6,false,false,false,4,false><<<dim3(32,5,2),256,0,stream>>>(q);

  k_to_cm<false><<<dim3(NK/64, CI/64, 2),256,0,stream>>>(VC, VCM, (long)NPIX*CI, (long)CI*NK);

  // position attention, per batch: E (chunked) -> softmax -> PV(split-K) -> epilogue
  for(int bb=0; bb<2; ++bb){
    for(int c0=0; c0<NPIX; c0+=1024){
      int Mc = NPIX - c0; if (Mc > 1024) Mc = 1024;
      GArgs e{};
      e.A = QC + (size_t)bb*NPIX*CQ + (size_t)c0*CQ;
      e.B = KC + (size_t)bb*NPIX*CQ;
      e.Cf = EB;
      e.M = Mc; e.N = NPIX; e.KT = 2; e.ktps = 2;
      e.lda = CQ; e.ldb = CQ; e.ldc = NPIX;
      e.Mclamp = Mc-1; e.Nclamp = NPIX-1;
      e.dR = dd + (size_t)bb*NPIX + c0; e.dC = dd + (size_t)bb*NPIX; e.lambp = lam;
      k_gemm<2,false,false,false,2,false><<<dim3((Mc+127)/128, 29, 1),256,0,stream>>>(e);
      k_softmax<<<Mc,256,0,stream>>>(EB, PB, c0);
    }
    hipMemsetAsync(SAF, 0, (size_t)NPIX*CI*4, stream);
    GArgs p{};
    p.A = PB; p.B = VCM + (size_t)bb*CI*NK;
    p.Cf = SAF;
    p.M = NPIX; p.N = CI; p.KT = NK/32; p.ktps = NK/32;
    p.lda = NK; p.ldb = NK; p.ldc = CI; p.sC = 0;
    p.Mclamp = NPIX-1; p.Nclamp = CI-1;
    p.ksplit = 2; p.kps = NK/64;
    k_gemm<3,false,false,false,4,true><<<dim3(29, 4, 2),256,0,stream>>>(p);
    k_pv_ep<<<dim3(NPIX*CI/8/256),256,0,stream>>>(SAF, F1 + (size_t)bb*PP*CI,
                                                  SAPM + (size_t)bb*(PP+2*GUARD)*CI + (size_t)GUARD*CI, gsa);
  }

  // channel attention: Gram with split-K atomics
  k_to_cm<true><<<dim3(NK/64, CI/64, 2),256,0,stream>>>(F2, F2CM, (long)PP*CI, (long)CI*NK);
  hipMemsetAsync(CEN, 0, (size_t)2*CI*CI*4, stream);
  GArgs c{};
  c.A = F2CM; c.B = F2CM; c.Cf = CEN;
  c.sA = (long)CI*NK; c.sB = (long)CI*NK; c.sC = (long)CI*CI;
  c.M = CI; c.N = CI; c.KT = NK/32; c.ktps = NK/32;
  c.lda = NK; c.ldb = NK; c.ldc = CI; c.Mclamp = CI-1; c.Nclamp = CI-1;
  c.ksplit = 8; c.kps = (NK/32 + 7)/8;
  k_gemm<3,false,false,false,1,true><<<dim3(4, 4, 16),256,0,stream>>>(c);
  k_csoftmax<<<dim3(CI,2),256,0,stream>>>(CEN, CATT);
  GArgs s{};
  s.A = F2; s.B = CATT;
  s.Cb = SCPM + (size_t)GUARD*CI;
  s.resid = F2; s.gamma = gsc;
  s.sA = (long)PP*CI; s.sB = (long)CI*CI; s.sC = (long)(PP+2*GUARD)*CI; s.sres = (long)PP*CI;
  s.M = PP; s.N = CI; s.KT = 16; s.ktps = 16;
  s.lda = CI; s.ldb = CI; s.ldc = CI; s.Mclamp = PP-1; s.Nclamp = CI-1;
  k_gemm<5,false,false,false,4,false><<<dim3(32, 4, 2),256,0,stream>>>(s);

  // post convs s1 + c1 fused (DUALZ), U=4
  k_wt<<<(512*512)/256,256,0,stream>>>(w_s1, WT1, 512);
  k_wt<<<(512*512)/256,256,0,stream>>>(w_c1, WT2, 512);
  GArgs t{};
  t.A = SAPM + (size_t)GUARD*CI; t.A2 = SCPM + (size_t)GUARD*CI;
  t.B = WT1; t.B2 = WT2;
  t.Cb = SACONV; t.Cb2 = SCCONV; t.bn = bn_s1; t.bn2 = bn_c1;
  t.sA = (long)(PP+2*GUARD)*CI; t.sB = 0; t.sC = (long)PP*CI;
  t.M = PP; t.N = CI; t.KT = 144; t.ktps = 16;
  t.lda = CI; t.ldb = 9*512; t.ldc = CI; t.Mclamp = PP-1; t.Nclamp = CI-1;
  k_gemm<0,true,false,true,4,false><<<dim3(32,4,4),256,0,stream>>>(t);

  // fused heads
  k_head<<<dim3(57,2),256,0,stream>>>(SACONV, SCCONV, w6,b6,w7,b7,w8,b8, OUT);
}

// Round 5
// 952.714 us; speedup vs baseline: 2.0222x; 1.0006x over previous
//
#include <hip/hip_runtime.h>
#include <stdint.h>

#define DI __device__ __forceinline__

typedef unsigned short u16;
typedef unsigned int u32;
typedef __attribute__((ext_vector_type(8))) short short8;
typedef __attribute__((ext_vector_type(4))) float floatx4;

// ---------------- geometry ----------------
constexpr int NPIX = 3600;   // 60*60
constexpr int NK   = 3712;   // 3600 padded to multiple of 128 (zero tail)
constexpr int PP   = 4096;   // 64*64 padded pixel grid (image at [2..61]^2)
constexpr int GUARD= 128;    // guard rows on padded-pixel tensors (shifted reads)
constexpr int CIN  = 2048, CI = 512, CQ = 64;

// ---------------- ws layout (bytes) ----------------
// R1 time-shared: XPM (convs) -> EBUF(+SAF)/PBUF (attention) -> SACONV/SCCONV (tail)
constexpr size_t OFF_XPM    = 0;                       // 2*4352*2048*2 = 35,651,584
constexpr size_t OFF_EBUF   = 0;                       // 1024*3600*4   = 14,745,600 (also SAF 3600*512*4)
constexpr size_t OFF_PBUF   = 14745600;                // 3600*3712*2   = 26,726,400 -> ends 41,472,000
constexpr size_t OFF_SACONV = 0;                       // 4096*512*2    = 4,194,304*2b = 8,388,608
constexpr size_t OFF_SCCONV = 8388608;
constexpr size_t R1_END     = 42812416;
constexpr size_t OFF_FEAT1  = R1_END;                  // 8,388,608
constexpr size_t OFF_FEAT2  = OFF_FEAT1 + 8388608;
constexpr size_t OFF_SAPM   = OFF_FEAT2 + 8388608;     // 8,912,896
constexpr size_t OFF_SCPM   = OFF_SAPM + 8912896;
constexpr size_t OFF_W      = OFF_SCPM + 8912896;      // big region, 37,748,736 (WTT 1024x18432)
// inside W (time-shared with WTT / each other):
constexpr size_t OFF_WQB = OFF_W;                      // 64*512*2
constexpr size_t OFF_WKB = OFF_W + 65536;
constexpr size_t OFF_WVB = OFF_W + 131072;             // 512*512*2
constexpr size_t OFF_QC  = OFF_W + 655360;             // 2*3600*64*2
constexpr size_t OFF_KC  = OFF_W + 1576960;
constexpr size_t OFF_VC  = OFF_W + 2498560;            // 2*3600*512*2 -> ends +9,871,360
constexpr size_t OFF_WT1 = OFF_W;                      // 512*4608*2 (s1) — QC/KC/VC dead by then
constexpr size_t OFF_WT2 = OFF_W + 4718592;            // 512*4608*2 (c1)
constexpr size_t OFF_VCM = OFF_W + 9871360;            // 2*512*3712*2 = 7,602,176 (shared w/ F2CM)
constexpr size_t OFF_CEN = OFF_W + 17473536;           // 2*512*512*4 = 2,097,152
constexpr size_t OFF_CATT= OFF_W + 19570688;           // 2*512*512*2 = 1,048,576 -> ends +20,619,264
constexpr size_t WS_NEED = OFF_W + 37748736;           // 115,164,160 (same as proven round 3)

// ---------------- helpers ----------------
DI float b2f(u16 s){ u32 u = ((u32)s)<<16; float f; __builtin_memcpy(&f,&u,4); return f; }
DI u16 f2b(float f){ u32 u; __builtin_memcpy(&u,&f,4); u32 r=(u+0x7fffu+((u>>16)&1u))>>16; return (u16)r; }
DI int pad_of(int n){ int y=n/60, x=n-y*60; return ((y+2)<<6)+x+2; }
DI bool interior(int p){ int py=p>>6, px=p&63; return (py>=2)&&(py<62)&&(px>=2)&&(px<62); }
DI int compact_of(int p){ return ((p>>6)-2)*60 + (p&63) - 2; }
DI void gll16(const void* g, void* l){
  __builtin_amdgcn_global_load_lds((const __attribute__((address_space(1))) void*)g,
                                   (__attribute__((address_space(3))) void*)l, 16, 0, 0);
}
DI float wred_max(float v){
#pragma unroll
  for(int m=32;m;m>>=1) v=fmaxf(v,__shfl_xor(v,m,64));
  return v;
}
DI float wred_min(float v){
#pragma unroll
  for(int m=32;m;m>>=1) v=fminf(v,__shfl_xor(v,m,64));
  return v;
}
DI float wred_sum(float v){
#pragma unroll
  for(int m=32;m;m>>=1) v+=__shfl_xor(v,m,64);
  return v;
}

// ---------------- NT GEMM: C[M,N] = sum_k A[m,k]*B[n,k] (A,B bf16) ----------------
// MODE 0: conv epilogue relu(bn(acc)) -> bf16, interior rows. NCAT: gc>=nsplit -> {Cb2,bn2}.
//         DUALZ: bz>>1 selects {A2,B2,Cb2,bn2}, bz&1 = batch.
// MODE 2: energy acc+lam*(dR-dC)^2 -> f32
// MODE 3: plain f32 (SPLITK: atomicAdd into zeroed Cf)
// MODE 5: sc: gamma*acc+resid[gr,gc] -> bf16, interior gr
// MODE 6: qkv concat: gc<64 -> QC(+bq), <128 -> KC(+bk), else VC(+bv); compact rows
struct GArgs {
  const u16 *A, *A2, *B, *B2; u16 *Cb, *Cb2, *Cb3; float* Cf;
  const u16* resid;
  const float *bn, *bn2, *bias, *bias2, *bias3, *gamma, *lambp, *dR, *dC;
  long sA, sB, sC, sres;
  int M, N, KT, ktps, lda, ldb, ldc, Mclamp, Nclamp, nsplit, ksplit, kps;
};

template<int MODE, bool SHIFT, bool NCAT, bool DUALZ, int U, bool SPLITK>
__global__ __launch_bounds__(256) void k_gemm(GArgs g){
  __shared__ alignas(16) short As[U*4096];
  __shared__ alignas(16) short Bs[U*4096];
  const int bz = blockIdx.z;
  const int sel = DUALZ ? (bz>>1) : 0;
  int bt  = DUALZ ? (bz&1)  : bz;
  int slice = 0;
  if constexpr(SPLITK){ bt = bz / g.ksplit; slice = bz - bt*g.ksplit; }
  const u16* Ab = ((DUALZ && sel) ? g.A2 : g.A) + (long)bt*g.sA;
  const u16* Bb = ((DUALZ && sel) ? g.B2 : g.B) + (long)bt*g.sB;
  const int m0 = blockIdx.x*128, n0 = blockIdx.y*128;
  const int tid = threadIdx.x, wid = tid>>6, lane = tid&63;
  const int wr = wid>>1, wc = wid&1;
  const int fr = lane&15, fq = lane>>4;
  const int srow = lane>>2;
  const int swz = ((lane&3) ^ ((lane>>3)&3)) << 3;   // swizzled 8-short slot within 32-short row

  long raB[2], rbB[2];
#pragma unroll
  for(int h=0;h<2;h++){
    long ra = m0 + wid*32 + h*16 + srow;
    if (!SHIFT) ra = (ra > g.Mclamp) ? (long)g.Mclamp : ra;
    raB[h] = ra*(long)g.lda + swz;
    long rb = n0 + wid*32 + h*16 + srow;
    rb = (rb > g.Nclamp) ? (long)g.Nclamp : rb;
    rbB[h] = rb*(long)g.ldb + swz;
  }
  const int ldsOff[2] = { (wid*32)*64, (wid*32+16)*64 };   // byte offsets within one buffer
  const int rswz = (fq ^ ((fr>>1)&3)) << 3;                // read-side slot (same involution)
  const int aRdO = (wr*64+fr)*32 + rswz;                   // shorts, within one buffer
  const int bRdO = (wc*64+fr)*32 + rswz;

  floatx4 acc[4][4];
#pragma unroll
  for(int i=0;i<4;i++)
#pragma unroll
    for(int j=0;j<4;j++)
#pragma unroll
      for(int e=0;e<4;e++) acc[i][j][e]=0.f;

  if constexpr(SHIFT){
    const int KB = g.ktps;
    for(int s=0; s<9; ++s){
      const long aoff = (long)((s/3)*64 + (s-(s/3)*3) - 65)*g.lda; // (ky-1)*64+(kx-1)
      const long boff = (long)s*KB*32;
      for(int kb=0; kb<KB; kb+=U){
        __syncthreads();
#pragma unroll
        for(int u=0;u<U;++u){
          const int ko = (kb+u)*32;
#pragma unroll
          for(int h=0;h<2;h++){
            gll16(Ab + raB[h] + aoff + ko, (char*)As + u*8192 + ldsOff[h]);
            gll16(Bb + rbB[h] + boff + ko, (char*)Bs + u*8192 + ldsOff[h]);
          }
        }
        __syncthreads();
#pragma unroll
        for(int u=0;u<U;++u){
          short8 af[4], bfv[4];
#pragma unroll
          for(int mi=0;mi<4;mi++) af[mi]  = *(const short8*)(As + u*4096 + aRdO + mi*512);
#pragma unroll
          for(int ni=0;ni<4;ni++) bfv[ni] = *(const short8*)(Bs + u*4096 + bRdO + ni*512);
#pragma unroll
          for(int mi=0;mi<4;mi++)
#pragma unroll
            for(int ni=0;ni<4;ni++)
              acc[mi][ni] = __builtin_amdgcn_mfma_f32_16x16x32_bf16(af[mi], bfv[ni], acc[mi][ni], 0,0,0);
        }
      }
    }
  } else {
    int kt0 = 0, ktN = g.KT;
    if constexpr(SPLITK){ kt0 = slice*g.kps; ktN = min(g.KT, kt0+g.kps); }
    for(int kt=kt0; kt<ktN; kt+=U){
      __syncthreads();
#pragma unroll
      for(int u=0;u<U;++u){
        if (kt+u < ktN){
          const int ko = (kt+u)*32;
#pragma unroll
          for(int h=0;h<2;h++){
            gll16(Ab + raB[h] + ko, (char*)As + u*8192 + ldsOff[h]);
            gll16(Bb + rbB[h] + ko, (char*)Bs + u*8192 + ldsOff[h]);
          }
        }
      }
      __syncthreads();
#pragma unroll
      for(int u=0;u<U;++u){
        if (kt+u < ktN){
          short8 af[4], bfv[4];
#pragma unroll
          for(int mi=0;mi<4;mi++) af[mi]  = *(const short8*)(As + u*4096 + aRdO + mi*512);
#pragma unroll
          for(int ni=0;ni<4;ni++) bfv[ni] = *(const short8*)(Bs + u*4096 + bRdO + ni*512);
#pragma unroll
          for(int mi=0;mi<4;mi++)
#pragma unroll
            for(int ni=0;ni<4;ni++)
              acc[mi][ni] = __builtin_amdgcn_mfma_f32_16x16x32_bf16(af[mi], bfv[ni], acc[mi][ni], 0,0,0);
        }
      }
    }
  }

  float* Cf = (MODE==2||MODE==3) ? g.Cf + (long)bt*g.sC : nullptr;
  const u16* Rb = (MODE==5) ? g.resid + (long)bt*g.sres : nullptr;
  float lamv=0.f, gamv=0.f;
  if constexpr(MODE==2) lamv = *g.lambp;
  if constexpr(MODE==5) gamv = *g.gamma;

#pragma unroll
  for(int ni=0;ni<4;ni++){
    const int gc = n0 + wc*64 + ni*16 + fr;
    if (gc >= g.N) continue;
    if constexpr(MODE==0){
      const float* bnP = g.bn; u16* CbP = g.Cb; int oc = gc;
      if constexpr(DUALZ){ if (sel){ bnP = g.bn2; CbP = g.Cb2; } }
      if constexpr(NCAT){ if (gc >= g.nsplit){ bnP = g.bn2; CbP = g.Cb2; oc = gc - g.nsplit; } }
      CbP += (long)bt*g.sC;
      const float s_=bnP[oc], bb=bnP[CI+oc], mm=bnP[2*CI+oc], vv=bnP[3*CI+oc];
      const float cA = s_*rsqrtf(vv+1e-5f), cB = bb - cA*mm;
#pragma unroll
      for(int mi=0;mi<4;mi++)
#pragma unroll
        for(int j=0;j<4;j++){
          const int gr = m0 + wr*64 + mi*16 + fq*4 + j;
          if (interior(gr)) CbP[(size_t)gr*g.ldc + oc] = f2b(fmaxf(cA*acc[mi][ni][j]+cB, 0.f));
        }
    } else if constexpr(MODE==6){
      u16* dst; int col, ld; float bs;
      if (gc < 64){ dst = g.Cb  + (long)bt*((long)NPIX*CQ); col=gc;     ld=CQ; bs=g.bias[gc]; }
      else if (gc < 128){ dst = g.Cb2 + (long)bt*((long)NPIX*CQ); col=gc-64; ld=CQ; bs=g.bias2[gc-64]; }
      else { dst = g.Cb3 + (long)bt*((long)NPIX*CI); col=gc-128; ld=CI; bs=g.bias3[gc-128]; }
#pragma unroll
      for(int mi=0;mi<4;mi++)
#pragma unroll
        for(int j=0;j<4;j++){
          const int gr = m0 + wr*64 + mi*16 + fq*4 + j;
          if (interior(gr)) dst[(size_t)compact_of(gr)*ld + col] = f2b(acc[mi][ni][j] + bs);
        }
    } else if constexpr(MODE==2){
      const float dc = g.dC[gc];
#pragma unroll
      for(int mi=0;mi<4;mi++)
#pragma unroll
        for(int j=0;j<4;j++){
          const int gr = m0 + wr*64 + mi*16 + fq*4 + j;
          if (gr < g.M){ const float t=g.dR[gr]-dc; Cf[(size_t)gr*g.ldc + gc] = acc[mi][ni][j] + lamv*t*t; }
        }
    } else if constexpr(MODE==3){
#pragma unroll
      for(int mi=0;mi<4;mi++)
#pragma unroll
        for(int j=0;j<4;j++){
          const int gr = m0 + wr*64 + mi*16 + fq*4 + j;
          if (gr < g.M){
            if constexpr(SPLITK) atomicAdd(&Cf[(size_t)gr*g.ldc + gc], acc[mi][ni][j]);
            else Cf[(size_t)gr*g.ldc + gc] = acc[mi][ni][j];
          }
        }
    } else if constexpr(MODE==5){
      u16* CbP = g.Cb + (long)bt*g.sC;
#pragma unroll
      for(int mi=0;mi<4;mi++)
#pragma unroll
        for(int j=0;j<4;j++){
          const int gr = m0 + wr*64 + mi*16 + fq*4 + j;
          if (interior(gr)){ const size_t o=(size_t)gr*g.ldc + gc; CbP[o] = f2b(gamv*acc[mi][ni][j] + b2f(Rb[o])); }
        }
    }
  }
}

// ---------------- x f32 [B,2048,3600] -> padded pixel-major bf16 [B][4352][2048] ----------------
__global__ __launch_bounds__(256) void k_padx(const float* __restrict__ x, u16* __restrict__ xpm){
  __shared__ alignas(16) u16 t[64][72];
  const int n0 = blockIdx.x*64, c0 = blockIdx.y*64, b = blockIdx.z;
  const float* xb = x + (size_t)b*CIN*NPIX;
  u16* ob = xpm + (size_t)b*(PP+2*GUARD)*CIN + (size_t)GUARD*CIN;
  const int tid = threadIdx.x;
#pragma unroll
  for(int pass=0; pass<2; ++pass){
    const int cl = pass*32 + (tid>>3);
    const int nn = (tid&7)*8;
    const int n = n0 + nn;
    const float* src = xb + (size_t)(c0+cl)*NPIX + n;
    u16 r[8];
    if (n + 7 < NPIX){
      const float4 v0 = *(const float4*)src;
      const float4 v1 = *(const float4*)(src+4);
      r[0]=f2b(v0.x); r[1]=f2b(v0.y); r[2]=f2b(v0.z); r[3]=f2b(v0.w);
      r[4]=f2b(v1.x); r[5]=f2b(v1.y); r[6]=f2b(v1.z); r[7]=f2b(v1.w);
    } else {
#pragma unroll
      for(int j=0;j<8;j++){ const int nj=n+j; r[j] = (nj<NPIX)? f2b(src[j]) : (u16)0; }
    }
    __builtin_memcpy(&t[cl][nn], r, 16);
  }
  __syncthreads();
#pragma unroll
  for(int pass=0; pass<2; ++pass){
    const int nl = pass*32 + (tid>>3);
    const int cc = (tid&7)*8;
    const int n = n0 + nl;
    if (n < NPIX){
      u16 v[8];
#pragma unroll
      for(int j=0;j<8;j++) v[j] = t[cc+j][nl];
      uint4 vv; __builtin_memcpy(&vv, v, 16);
      *(uint4*)(ob + (size_t)pad_of(n)*CIN + c0 + cc) = vv;
    }
  }
}

// ---------------- bf16 [rows, 512] pixel-major -> [512, NK] channel-major (zero tail) ----------------
template<bool PADIN>
__global__ __launch_bounds__(256) void k_to_cm(const u16* __restrict__ in, u16* __restrict__ out,
                                               long sIn, long sOut){
  __shared__ alignas(16) u16 t[64][72];
  const int n0 = blockIdx.x*64, c0 = blockIdx.y*64, b = blockIdx.z;
  const u16* ib = in + (size_t)b*sIn;
  u16* ob = out + (size_t)b*sOut;
  const int tid = threadIdx.x;
#pragma unroll
  for(int pass=0; pass<2; ++pass){
    const int nl = pass*32 + (tid>>3);
    const int cc = (tid&7)*8;
    const int n = n0 + nl;
    uint4 v = {0,0,0,0};
    if (n < NPIX){
      const int r = PADIN ? pad_of(n) : n;
      v = *(const uint4*)(ib + (size_t)r*CI + c0 + cc);
    }
    *(uint4*)&t[nl][cc] = v;
  }
  __syncthreads();
#pragma unroll
  for(int pass=0; pass<2; ++pass){
    const int cl = pass*32 + (tid>>3);
    const int nn = (tid&7)*8;
    const int n = n0 + nn;
    if (n < NK){
      u16 v[8];
#pragma unroll
      for(int j=0;j<8;j++) v[j] = t[nn+j][cl];
      uint4 vv; __builtin_memcpy(&vv, v, 16);
      *(uint4*)(ob + (size_t)(c0+cl)*NK + n) = vv;
    }
  }
}

// ---------------- w f32 [O,Kc,3,3] -> Wt bf16 [O, 9*Kc], Wt[o, s*Kc+i] = w[o,i,s] ----------------
__global__ __launch_bounds__(256) void k_wt(const float* __restrict__ w, u16* __restrict__ wt, int Kc){
  const int idx = blockIdx.x*256 + threadIdx.x;
  const int o = idx / Kc, i = idx - o*Kc;
  u16 v[9];
#pragma unroll
  for(int s=0;s<9;s++) v[s] = f2b(w[(size_t)idx*9 + s]);
#pragma unroll
  for(int s=0;s<9;s++) wt[(size_t)o*9*Kc + (size_t)s*Kc + i] = v[s];
}

// ---------------- f32 -> bf16 elementwise ----------------
__global__ __launch_bounds__(256) void k_cvt(const float* __restrict__ src, u16* __restrict__ dst, int n){
  const int i = blockIdx.x*256 + threadIdx.x;
  if (i < n) dst[i] = f2b(src[i]);
}

// ---------------- row softmax: E[r, 0..3599] f32 -> P[(c0+r), 0..NK-1] bf16 ----------------
__global__ __launch_bounds__(256) void k_softmax(const float* __restrict__ E, u16* __restrict__ P, int c0){
  __shared__ float row[NK];
  __shared__ float red[8];
  const int r = blockIdx.x, tid = threadIdx.x;
  const float* e = E + (size_t)r*NPIX;
  float lmax = -3e38f;
  for(int i=tid;i<NK;i+=256){
    const float v = (i<NPIX)? e[i] : -3e38f;
    row[i]=v; lmax=fmaxf(lmax,v);
  }
  lmax = wred_max(lmax);
  if((tid&63)==0) red[tid>>6]=lmax;
  __syncthreads();
  const float m = fmaxf(fmaxf(red[0],red[1]),fmaxf(red[2],red[3]));
  float ls=0.f;
  for(int i=tid;i<NK;i+=256){
    const float v=__expf(row[i]-m);
    row[i]=v; ls+=v;
  }
  ls = wred_sum(ls);
  if((tid&63)==0) red[4+(tid>>6)]=ls;
  __syncthreads();
  const float inv = 1.f/(red[4]+red[5]+red[6]+red[7]);
  u16* po = P + (size_t)(c0+r)*NK;
  for(int i=tid;i<NK;i+=256) po[i]=f2b(row[i]*inv);
}

// ---------------- channel softmax ----------------
__global__ __launch_bounds__(256) void k_csoftmax(const float* __restrict__ cen, u16* __restrict__ catt){
  const int c = blockIdx.x, b = blockIdx.y, tid = threadIdx.x;
  const float* e = cen + ((size_t)b*CI + c)*CI;
  u16* o = catt + ((size_t)b*CI + c)*CI;
  __shared__ float red[8];
  const float a0 = e[tid], a1 = e[tid+256];
  float lmin = fminf(a0,a1);
  lmin = wred_min(lmin);
  if((tid&63)==0) red[tid>>6]=lmin;
  __syncthreads();
  const float m0 = fminf(fminf(red[0],red[1]),fminf(red[2],red[3]));
  const float x0 = __expf(m0-a0), x1 = __expf(m0-a1);
  float ls = x0+x1;
  ls = wred_sum(ls);
  if((tid&63)==0) red[4+(tid>>6)]=ls;
  __syncthreads();
  const float inv = 1.f/(red[4]+red[5]+red[6]+red[7]);
  o[tid] = f2b(x0*inv); o[tid+256] = f2b(x1*inv);
}

// ---------------- PV epilogue: SAPM[pad(n),c] = gamma*SAF[n,c] + F1[pad(n),c] ----------------
__global__ __launch_bounds__(256) void k_pv_ep(const float* __restrict__ saf, const u16* __restrict__ f1,
                                               u16* __restrict__ sapm, const float* __restrict__ gamma){
  const int idx = blockIdx.x*256 + threadIdx.x;   // 230400 threads, 8 elems each
  const int n = idx >> 6, c = (idx & 63) * 8;
  const float gam = *gamma;
  const int p = pad_of(n);
  const float4 v0 = *(const float4*)(saf + (size_t)n*CI + c);
  const float4 v1 = *(const float4*)(saf + (size_t)n*CI + c + 4);
  const uint4 rv = *(const uint4*)(f1 + (size_t)p*CI + c);
  const u16* rp = (const u16*)&rv;
  u16 o[8];
  o[0]=f2b(gam*v0.x + b2f(rp[0])); o[1]=f2b(gam*v0.y + b2f(rp[1]));
  o[2]=f2b(gam*v0.z + b2f(rp[2])); o[3]=f2b(gam*v0.w + b2f(rp[3]));
  o[4]=f2b(gam*v1.x + b2f(rp[4])); o[5]=f2b(gam*v1.y + b2f(rp[5]));
  o[6]=f2b(gam*v1.z + b2f(rp[6])); o[7]=f2b(gam*v1.w + b2f(rp[7]));
  uint4 ov; __builtin_memcpy(&ov, o, 16);
  *(uint4*)(sapm + (size_t)p*CI + c) = ov;
}

// ---------------- fused 1x1 head ----------------
__global__ __launch_bounds__(256) void k_head(const u16* __restrict__ sa, const u16* __restrict__ sc,
    const float* __restrict__ w6, const float* __restrict__ b6,
    const float* __restrict__ w7, const float* __restrict__ b7,
    const float* __restrict__ w8, const float* __restrict__ b8,
    float* __restrict__ out){
  __shared__ float fa[64][65], fb[64][65];
  __shared__ float wf[3][40][64];
  const int n0 = blockIdx.x*64, b = blockIdx.y;
  const u16* sab = sa + (size_t)b*PP*CI;
  const u16* scb = sc + (size_t)b*PP*CI;
  const int tid = threadIdx.x;
  const int px = tid & 63, og = tid >> 6;
  float a6[10], a7[10], a8[10];
#pragma unroll
  for(int i=0;i<10;i++){ a6[i]=0.f; a7[i]=0.f; a8[i]=0.f; }
  for(int cc0=0; cc0<CI; cc0+=64){
    __syncthreads();
#pragma unroll
    for(int pass=0; pass<2; ++pass){
      const int rl = pass*32 + (tid>>3);
      const int cq = (tid&7)*8;
      const int n = n0 + rl;
      const int prow = pad_of(n < NPIX ? n : NPIX-1);
      const uint4 va = *(const uint4*)(sab + (size_t)prow*CI + cc0 + cq);
      const uint4 vb = *(const uint4*)(scb + (size_t)prow*CI + cc0 + cq);
      const u16* pa = (const u16*)&va; const u16* pb = (const u16*)&vb;
#pragma unroll
      for(int j=0;j<8;j++){ fa[rl][cq+j] = b2f(pa[j]); fb[rl][cq+j] = b2f(pb[j]); }
    }
    for(int i=tid; i<40*64; i+=256){
      const int o = i>>6, c = i&63;
      wf[0][o][c] = w6[(size_t)o*CI + cc0 + c];
      wf[1][o][c] = w7[(size_t)o*CI + cc0 + c];
      wf[2][o][c] = w8[(size_t)o*CI + cc0 + c];
    }
    __syncthreads();
    for(int cl=0; cl<64; ++cl){
      const float va = fa[px][cl], vb = fb[px][cl], vs = va+vb;
#pragma unroll
      for(int oo=0;oo<10;oo++){
        const int o = og*10+oo;
        a6[oo] += wf[0][o][cl]*va;
        a7[oo] += wf[1][o][cl]*vb;
        a8[oo] += wf[2][o][cl]*vs;
      }
    }
  }
  const int n = n0 + px;
  if (n < NPIX){
#pragma unroll
    for(int oo=0;oo<10;oo++){
      const int o = og*10+oo;
      out[(size_t)b*144000 + (size_t)o*NPIX + n]          = a8[oo] + b8[o]; // sasc
      out[288000 + (size_t)b*144000 + (size_t)o*NPIX + n] = a6[oo] + b6[o]; // sa_output
      out[576000 + (size_t)b*144000 + (size_t)o*NPIX + n] = a7[oo] + b7[o]; // sc_output
    }
  }
}

// ---------------- launch ----------------
extern "C" void kernel_launch(void* const* d_in, const int* in_sizes, int n_in,
                              void* d_out, int out_size, void* d_ws, size_t ws_size,
                              hipStream_t stream){
  (void)in_sizes; (void)n_in; (void)out_size;
  if (ws_size < WS_NEED) return;

  const float* x    = (const float*)d_in[0];
  const float* dd   = (const float*)d_in[1];
  const float* w_s0 = (const float*)d_in[2];
  const float* bn_s0= (const float*)d_in[3];
  const float* wq   = (const float*)d_in[4];
  const float* bq   = (const float*)d_in[5];
  const float* wk   = (const float*)d_in[6];
  const float* bk   = (const float*)d_in[7];
  const float* wv   = (const float*)d_in[8];
  const float* bv   = (const float*)d_in[9];
  const float* gsa  = (const float*)d_in[10];
  const float* lam  = (const float*)d_in[11];
  const float* w_s1 = (const float*)d_in[12];
  const float* bn_s1= (const float*)d_in[13];
  const float* w6   = (const float*)d_in[14];
  const float* b6   = (const float*)d_in[15];
  const float* w_c0 = (const float*)d_in[16];
  const float* bn_c0= (const float*)d_in[17];
  const float* gsc  = (const float*)d_in[18];
  const float* w_c1 = (const float*)d_in[19];
  const float* bn_c1= (const float*)d_in[20];
  const float* w7   = (const float*)d_in[21];
  const float* b7   = (const float*)d_in[22];
  const float* w8   = (const float*)d_in[23];
  const float* b8   = (const float*)d_in[24];

  char* W = (char*)d_ws;
  u16*   XPM   = (u16*)(W + OFF_XPM);
  float* EB    = (float*)(W + OFF_EBUF);
  float* SAF   = (float*)(W + OFF_EBUF);   // time-shared with EB
  u16*   PB    = (u16*)(W + OFF_PBUF);
  u16*   SACONV= (u16*)(W + OFF_SACONV);
  u16*   SCCONV= (u16*)(W + OFF_SCCONV);
  u16*   F1    = (u16*)(W + OFF_FEAT1);
  u16*   F2    = (u16*)(W + OFF_FEAT2);
  u16*   SAPM  = (u16*)(W + OFF_SAPM);
  u16*   SCPM  = (u16*)(W + OFF_SCPM);
  u16*   WTT   = (u16*)(W + OFF_W);
  u16*   WQB   = (u16*)(W + OFF_WQB);
  u16*   WKB   = (u16*)(W + OFF_WKB);
  u16*   WVB   = (u16*)(W + OFF_WVB);
  u16*   QC    = (u16*)(W + OFF_QC);
  u16*   KC    = (u16*)(W + OFF_KC);
  u16*   VC    = (u16*)(W + OFF_VC);
  u16*   WT1   = (u16*)(W + OFF_WT1);
  u16*   WT2   = (u16*)(W + OFF_WT2);
  u16*   VCM   = (u16*)(W + OFF_VCM);
  u16*   F2CM  = VCM;                     // time-shared
  float* CEN   = (float*)(W + OFF_CEN);
  u16*   CATT  = (u16*)(W + OFF_CATT);
  float* OUT   = (float*)d_out;

  // zero padded tensors (ring + guards must be 0 for shifted conv reads)
  hipMemsetAsync(XPM,  0, (size_t)2*(PP+2*GUARD)*CIN*2, stream);
  hipMemsetAsync(SAPM, 0, (size_t)2*(PP+2*GUARD)*CI*2,  stream);
  hipMemsetAsync(SCPM, 0, (size_t)2*(PP+2*GUARD)*CI*2,  stream);

  k_padx<<<dim3(57,32,2),256,0,stream>>>(x, XPM);

  // conv s0 + c0 fused (N-concat), U=4 (BK=128)
  k_wt<<<(512*2048)/256,256,0,stream>>>(w_s0, WTT, 2048);
  k_wt<<<(512*2048)/256,256,0,stream>>>(w_c0, WTT + (size_t)512*9*2048, 2048);
  GArgs a{};
  a.A = XPM + (size_t)GUARD*CIN; a.B = WTT; a.Cb = F1; a.Cb2 = F2;
  a.bn = bn_s0; a.bn2 = bn_c0;
  a.sA = (long)(PP+2*GUARD)*CIN; a.sB = 0; a.sC = (long)PP*CI;
  a.M = PP; a.N = 1024; a.nsplit = 512; a.KT = 576; a.ktps = 64;
  a.lda = CIN; a.ldb = 9*2048; a.ldc = CI; a.Mclamp = PP-1; a.Nclamp = 1023;
  k_gemm<0,true,true,false,4,false><<<dim3(32,8,2),256,0,stream>>>(a);

  // bf16 copies of 1x1 weights (concat [wq;wk;wv] = 640x512)
  k_cvt<<<(64*512+255)/256,256,0,stream>>>(wq, WQB, 64*512);
  k_cvt<<<(64*512+255)/256,256,0,stream>>>(wk, WKB, 64*512);
  k_cvt<<<(512*512+255)/256,256,0,stream>>>(wv, WVB, 512*512);

  // q,k,v in one GEMM (N=640), U=4
  GArgs q{};
  q.A = F1; q.sA = (long)PP*CI; q.lda = CI;
  q.M = PP; q.Mclamp = PP-1; q.KT = 16; q.ktps = 16;
  q.B = WQB; q.sB = 0; q.ldb = CI; q.N = 640; q.Nclamp = 639;
  q.Cb = QC; q.Cb2 = KC; q.Cb3 = VC; q.bias = bq; q.bias2 = bk; q.bias3 = bv;
  k_gemm<6,false,false,false,4,false><<<dim3(32,5,2),256,0,stream>>>(q);

  k_to_cm<false><<<dim3(NK/64, CI/64, 2),256,0,stream>>>(VC, VCM, (long)NPIX*CI, (long)CI*NK);

  // position attention, per batch: E (chunked) -> softmax -> PV(split-K) -> epilogue
  for(int bb=0; bb<2; ++bb){
    for(int c0=0; c0<NPIX; c0+=1024){
      int Mc = NPIX - c0; if (Mc > 1024) Mc = 1024;
      GArgs e{};
      e.A = QC + (size_t)bb*NPIX*CQ + (size_t)c0*CQ;
      e.B = KC + (size_t)bb*NPIX*CQ;
      e.Cf = EB;
      e.M = Mc; e.N = NPIX; e.KT = 2; e.ktps = 2;
      e.lda = CQ; e.ldb = CQ; e.ldc = NPIX;
      e.Mclamp = Mc-1; e.Nclamp = NPIX-1;
      e.dR = dd + (size_t)bb*NPIX + c0; e.dC = dd + (size_t)bb*NPIX; e.lambp = lam;
      k_gemm<2,false,false,false,2,false><<<dim3((Mc+127)/128, 29, 1),256,0,stream>>>(e);
      k_softmax<<<Mc,256,0,stream>>>(EB, PB, c0);
    }
    hipMemsetAsync(SAF, 0, (size_t)NPIX*CI*4, stream);
    GArgs p{};
    p.A = PB; p.B = VCM + (size_t)bb*CI*NK;
    p.Cf = SAF;
    p.M = NPIX; p.N = CI; p.KT = NK/32; p.ktps = NK/32;
    p.lda = NK; p.ldb = NK; p.ldc = CI; p.sC = 0;
    p.Mclamp = NPIX-1; p.Nclamp = CI-1;
    p.ksplit = 2; p.kps = NK/64;
    k_gemm<3,false,false,false,4,true><<<dim3(29, 4, 2),256,0,stream>>>(p);
    k_pv_ep<<<dim3(NPIX*CI/8/256),256,0,stream>>>(SAF, F1 + (size_t)bb*PP*CI,
                                                  SAPM + (size_t)bb*(PP+2*GUARD)*CI + (size_t)GUARD*CI, gsa);
  }

  // channel attention: Gram with split-K atomics
  k_to_cm<true><<<dim3(NK/64, CI/64, 2),256,0,stream>>>(F2, F2CM, (long)PP*CI, (long)CI*NK);
  hipMemsetAsync(CEN, 0, (size_t)2*CI*CI*4, stream);
  GArgs c{};
  c.A = F2CM; c.B = F2CM; c.Cf = CEN;
  c.sA = (long)CI*NK; c.sB = (long)CI*NK; c.sC = (long)CI*CI;
  c.M = CI; c.N = CI; c.KT = NK/32; c.ktps = NK/32;
  c.lda = NK; c.ldb = NK; c.ldc = CI; c.Mclamp = CI-1; c.Nclamp = CI-1;
  c.ksplit = 8; c.kps = (NK/32 + 7)/8;
  k_gemm<3,false,false,false,1,true><<<dim3(4, 4, 16),256,0,stream>>>(c);
  k_csoftmax<<<dim3(CI,2),256,0,stream>>>(CEN, CATT);
  GArgs s{};
  s.A = F2; s.B = CATT;
  s.Cb = SCPM + (size_t)GUARD*CI;
  s.resid = F2; s.gamma = gsc;
  s.sA = (long)PP*CI; s.sB = (long)CI*CI; s.sC = (long)(PP+2*GUARD)*CI; s.sres = (long)PP*CI;
  s.M = PP; s.N = CI; s.KT = 16; s.ktps = 16;
  s.lda = CI; s.ldb = CI; s.ldc = CI; s.Mclamp = PP-1; s.Nclamp = CI-1;
  k_gemm<5,false,false,false,4,false><<<dim3(32, 4, 2),256,0,stream>>>(s);

  // post convs s1 + c1 fused (DUALZ), U=4
  k_wt<<<(512*512)/256,256,0,stream>>>(w_s1, WT1, 512);
  k_wt<<<(512*512)/256,256,0,stream>>>(w_c1, WT2, 512);
  GArgs t{};
  t.A = SAPM + (size_t)GUARD*CI; t.A2 = SCPM + (size_t)GUARD*CI;
  t.B = WT1; t.B2 = WT2;
  t.Cb = SACONV; t.Cb2 = SCCONV; t.bn = bn_s1; t.bn2 = bn_c1;
  t.sA = (long)(PP+2*GUARD)*CI; t.sB = 0; t.sC = (long)PP*CI;
  t.M = PP; t.N = CI; t.KT = 144; t.ktps = 16;
  t.lda = CI; t.ldb = 9*512; t.ldc = CI; t.Mclamp = PP-1; t.Nclamp = CI-1;
  k_gemm<0,true,false,true,4,false><<<dim3(32,4,4),256,0,stream>>>(t);

  // fused heads
  k_head<<<dim3(57,2),256,0,stream>>>(SACONV, SCCONV, w6,b6,w7,b7,w8,b8, OUT);
}